// Round 16
// baseline (600.141 us; speedup 1.0000x reference)
//
#include <hip/hip_runtime.h>

typedef __bf16 bf16;
typedef __bf16 v4bf __attribute__((ext_vector_type(4)));
typedef __bf16 v8bf __attribute__((ext_vector_type(8)));
typedef float  v4f  __attribute__((ext_vector_type(4)));
typedef float  v16f __attribute__((ext_vector_type(16)));
typedef unsigned short u16;
typedef u16 v8us __attribute__((ext_vector_type(8)));
typedef unsigned int v4u __attribute__((ext_vector_type(4)));
typedef _Float16 f16;
typedef f16 v4h __attribute__((ext_vector_type(4)));

#define L_ 4
#define B_ 32
#define N_ 512
#define D_ 256
#define H_ 8
#define F_ 1024
#define ROWS (B_*N_)               // 16384
#define QHSZ ((size_t)B_*H_*N_*32) // elems per Q/K/V head-major section

__device__ __forceinline__ void gload16(const void* g, void* l) {
  __builtin_amdgcn_global_load_lds((__attribute__((address_space(1))) void*)g,
                                   (__attribute__((address_space(3))) void*)l,
                                   16, 0, 0);
}

__device__ __forceinline__ unsigned pk_bf16(float a, float b) {
  unsigned r;
  asm("v_cvt_pk_bf16_f32 %0, %1, %2" : "=v"(r) : "v"(a), "v"(b));
  return r;
}

// swap: a.hi <-> b.lo
#define PLSWAP(a, b) asm volatile("v_permlane32_swap_b32 %0, %1" : "+v"(a), "+v"(b))

#define EXP2(x) __builtin_amdgcn_exp2f(x)

// monotone float<->uint encoding for atomicMax
__device__ __forceinline__ unsigned encf(float f) {
  unsigned u = __float_as_uint(f);
  return (u & 0x80000000u) ? ~u : (u | 0x80000000u);
}
__device__ __forceinline__ float decf(unsigned e) {
  unsigned b = (e & 0x80000000u) ? (e & 0x7fffffffu) : ~e;
  return __uint_as_float(b);
}

template <int N> __device__ __forceinline__ void waitvm() {
  if constexpr (N == 0) asm volatile("s_waitcnt vmcnt(0)" ::: "memory");
  else if constexpr (N == 2) asm volatile("s_waitcnt vmcnt(2)" ::: "memory");
  else if constexpr (N == 3) asm volatile("s_waitcnt vmcnt(3)" ::: "memory");
  else if constexpr (N == 4) asm volatile("s_waitcnt vmcnt(4)" ::: "memory");
  else if constexpr (N == 5) asm volatile("s_waitcnt vmcnt(5)" ::: "memory");
  else if constexpr (N == 6) asm volatile("s_waitcnt vmcnt(6)" ::: "memory");
}

// ---------------- biasP (permuted, MFMA C-layout) = (eK @ eQ^T) * log2e; also mq = colmax ----------------
__global__ __launch_bounds__(256) void bias_gemm(
    const float* __restrict__ eK, const float* __restrict__ eQ,
    float* __restrict__ biasP, unsigned* __restrict__ mqe) {
  __shared__ float As[32][17];   // eK rows (k)
  __shared__ float Bs[32][17];   // eQ rows (q)
  __shared__ float pm[16][32];
  const int tx = threadIdx.x, ty = threadIdx.y;     // 16x16
  const int t = ty * 16 + tx;
  const int lrow = t >> 3, lkq = (t & 7) * 2;
  const int r0 = blockIdx.y * 32, c0 = blockIdx.x * 32;
  float acc[2][2] = {{0.f, 0.f}, {0.f, 0.f}};
  for (int k0 = 0; k0 < D_; k0 += 16) {
    const float2 a2 = *(const float2*)&eK[(size_t)(r0 + lrow) * D_ + k0 + lkq];
    const float2 b2 = *(const float2*)&eQ[(size_t)(c0 + lrow) * D_ + k0 + lkq];
    As[lrow][lkq] = a2.x; As[lrow][lkq + 1] = a2.y;
    Bs[lrow][lkq] = b2.x; Bs[lrow][lkq + 1] = b2.y;
    __syncthreads();
#pragma unroll
    for (int k = 0; k < 16; ++k) {
      const float a0 = As[ty * 2][k], a1 = As[ty * 2 + 1][k];
      const float b0 = Bs[tx * 2][k], b1 = Bs[tx * 2 + 1][k];
      acc[0][0] += a0 * b0; acc[0][1] += a0 * b1;
      acc[1][0] += a1 * b0; acc[1][1] += a1 * b1;
    }
    __syncthreads();
  }
#pragma unroll
  for (int i = 0; i < 2; ++i)
#pragma unroll
    for (int j = 0; j < 2; ++j) acc[i][j] *= 1.4426950408889634f;
#pragma unroll
  for (int i = 0; i < 2; ++i) {
    const int gr = r0 + ty * 2 + i;
    const int kb = gr >> 5, r5 = gr & 31;
    const int blk = kb * 8 + (r5 >> 3) * 2 + ((r5 >> 2) & 1);
#pragma unroll
    for (int j = 0; j < 2; ++j) {
      const int q = c0 + tx * 2 + j;
      biasP[(size_t)(blk * 512 + q) * 4 + (r5 & 3)] = acc[i][j];
    }
  }
  pm[ty][tx * 2]     = fmaxf(acc[0][0], acc[1][0]);
  pm[ty][tx * 2 + 1] = fmaxf(acc[0][1], acc[1][1]);
  __syncthreads();
  if (ty == 0) {
#pragma unroll
    for (int j = 0; j < 2; ++j) {
      float m = pm[0][tx * 2 + j];
#pragma unroll
      for (int y = 1; y < 16; ++y) m = fmaxf(m, pm[y][tx * 2 + j]);
      atomicMax(&mqe[c0 + tx * 2 + j], encf(m));
    }
  }
}

// ---------------- unified setup: init_x + pack_bqkv + all weight transposes + subm->fp16 ----------------
__device__ __forceinline__ void convT_tile(
    const float* __restrict__ W, bf16* __restrict__ Wt,
    int K, int N, size_t inL, size_t outL, int l, int k0, int n0, int tid,
    float (*t)[33]) {
  const int r = tid >> 5, c = tid & 31;
#pragma unroll
  for (int i = 0; i < 4; ++i)
    t[r + 8 * i][c] = W[l * inL + (size_t)(k0 + r + 8 * i) * N + n0 + c];
  __syncthreads();
#pragma unroll
  for (int i = 0; i < 4; ++i)
    Wt[l * outL + (size_t)(n0 + r + 8 * i) * K + k0 + c] = (bf16)t[c][r + 8 * i];
}

// blocks: [0,4096) init_x | [4096,4108) pack_bqkv | [4108,5132) Wq/Wk/Wv/Wo |
//         [5132,6156) W1 | [6156,7180) W2 | [7180,7436) subm: biasH = f16(biasP - mq)
__global__ __launch_bounds__(256) void setup_all(
    const float* __restrict__ src, bf16* __restrict__ xb,
    const float* __restrict__ bq, const float* __restrict__ bk,
    const float* __restrict__ bv, float* __restrict__ bqkv,
    const float* __restrict__ Wq, const float* __restrict__ Wk,
    const float* __restrict__ Wv, const float* __restrict__ Wo,
    const float* __restrict__ W1, const float* __restrict__ W2,
    bf16* __restrict__ Wqkvt, bf16* __restrict__ Wot,
    bf16* __restrict__ W1t, bf16* __restrict__ W2t,
    const float* __restrict__ biasP, f16* __restrict__ biasH,
    const unsigned* __restrict__ mqe) {
  __shared__ float t[32][33];
  const int tid = threadIdx.x;
  int id = blockIdx.x;
  if (id < 4096) {
    const int i = id * 256 + tid;  // float4 index
    float4 v = ((const float4*)src)[i];
    uint2 w;
    w.x = pk_bf16(v.x, v.y);
    w.y = pk_bf16(v.z, v.w);
    ((uint2*)xb)[i] = w;
    return;
  }
  id -= 4096;
  if (id < 12) {
    const int i = id * 256 + tid;
    if (i < L_ * 768) {
      const int l = i / 768, n = i - l * 768;
      float v = (n < 256) ? bq[l * 256 + n]
              : (n < 512) ? bk[l * 256 + n - 256]
                          : bv[l * 256 + n - 512];
      bqkv[i] = v;
    }
    return;
  }
  id -= 12;
  if (id < 1024) {
    const int w = id >> 8, tt = id & 255;
    const int l = tt >> 6, tile = tt & 63;
    const int n0 = (tile & 7) * 32, k0 = (tile >> 3) * 32;
    const float* W = (w == 0) ? Wq : (w == 1) ? Wk : (w == 2) ? Wv : Wo;
    bf16* Wt = (w == 3) ? Wot : (Wqkvt + w * 65536);
    const size_t outL = (w == 3) ? 65536 : 196608;
    convT_tile(W, Wt, 256, 256, 65536, outL, l, k0, n0, tid, t);
    return;
  }
  id -= 1024;
  if (id < 1024) {
    const int l = id >> 8, tile = id & 255;
    const int n0 = (tile & 31) * 32, k0 = (tile >> 5) * 32;
    convT_tile(W1, W1t, 256, 1024, 262144, 262144, l, k0, n0, tid, t);
    return;
  }
  id -= 1024;
  if (id < 1024) {
    const int l = id >> 8, tile = id & 255;
    const int n0 = (tile & 7) * 32, k0 = (tile >> 3) * 32;
    convT_tile(W2, W2t, 1024, 256, 262144, 262144, l, k0, n0, tid, t);
    return;
  }
  id -= 1024;
  {
    const int i = id * 256 + tid;  // 65536 float4
    const float4 v = ((const float4*)biasP)[i];
    const float m = decf(mqe[i & 511]);
    v4h o;
    o[0] = (f16)(v.x - m); o[1] = (f16)(v.y - m);
    o[2] = (f16)(v.z - m); o[3] = (f16)(v.w - m);
    *(v4h*)&biasH[(size_t)i * 4] = o;
  }
}

// ---------------- bf16 MFMA GEMM, 2-phase pipelined, XCD-swizzled ----------------
// OUTMODE: 0 = fp32 row-major, 1 = bf16 row-major, 2 = bf16 head-major QKV (N=768)
template <int BM, int BN, int WPC, int RELU, int OUTMODE, int RESID>
__global__ __launch_bounds__(256, WPC) void gemm_bf16k(
    const bf16* __restrict__ A, const bf16* __restrict__ Bt,
    const float* __restrict__ bias, const bf16* __restrict__ resid,
    void* __restrict__ Cout, int M, int N, int K, int nbx) {
  constexpr int MR = BM / 32, NR = BN / 32;
  constexpr int NSLAB = (BM + BN) / 16;
  constexpr int LPW = NSLAB / 4;
  constexpr int BUFE = (BM + BN) * 32;
  __shared__ __align__(16) bf16 lds[3 * BUFE];
  const int tid  = threadIdx.x;
  const int wave = tid >> 6, lane = tid & 63;
  const int l15 = lane & 15, l4 = lane >> 4;
  const int qq = gridDim.x >> 3;
  const int wg = (blockIdx.x & 7) * qq + (blockIdx.x >> 3);
  const int bx = wg % nbx, by = wg / nbx;
  const int bm = by * BM, bn = bx * BN;
  const int wr = (wave >> 1) * (BM / 2), wc = (wave & 1) * (BN / 2);
  const int lrow = lane >> 2;
  const int lk   = (lane & 3) * 8;

  v4f acc[MR][NR];
#pragma unroll
  for (int m = 0; m < MR; ++m)
#pragma unroll
    for (int n = 0; n < NR; ++n) acc[m][n] = (v4f){0.f, 0.f, 0.f, 0.f};

  auto STAGE = [&](int buf, int k0) {
    bf16* dst = &lds[buf * BUFE];
#pragma unroll
    for (int s = wave; s < NSLAB; s += 4) {
      if (s < BM / 16)
        gload16(A + (size_t)(bm + s * 16 + lrow) * K + k0 + lk, dst + s * 512);
      else
        gload16(Bt + (size_t)(bn + (s - BM / 16) * 16 + lrow) * K + k0 + lk, dst + s * 512);
    }
  };

  const int nk = K >> 5;
  STAGE(0, 0);
  STAGE(1, 32);
  waitvm<LPW>();
  __builtin_amdgcn_s_barrier();
  __builtin_amdgcn_sched_barrier(0);

  int cur = 0;
  for (int t = 0; t < nk; ++t) {
    const bool pf = (t + 2 < nk);
    if (pf) STAGE(cur == 0 ? 2 : cur - 1, (t + 2) * 32);
    const bf16* buf = &lds[cur * BUFE];
    v8bf af[MR], bfr[NR];
#pragma unroll
    for (int m = 0; m < MR; ++m)
      af[m] = *(const v8bf*)&buf[(wr + m * 16 + l15) * 32 + l4 * 8];
#pragma unroll
    for (int n = 0; n < NR; ++n)
      bfr[n] = *(const v8bf*)&buf[BM * 32 + (wc + n * 16 + l15) * 32 + l4 * 8];
    __builtin_amdgcn_s_setprio(1);
#pragma unroll
    for (int m = 0; m < MR; ++m)
#pragma unroll
      for (int n = 0; n < NR; ++n)
        acc[m][n] = __builtin_amdgcn_mfma_f32_16x16x32_bf16(af[m], bfr[n], acc[m][n], 0, 0, 0);
    __builtin_amdgcn_s_setprio(0);
    if (pf) waitvm<LPW>();
    else    waitvm<0>();
    __builtin_amdgcn_s_barrier();
    __builtin_amdgcn_sched_barrier(0);
    cur = (cur == 2) ? 0 : cur + 1;
  }

#pragma unroll
  for (int m = 0; m < MR; ++m) {
    const int row0 = bm + wr + m * 16 + l4 * 4;
#pragma unroll
    for (int n = 0; n < NR; ++n) {
      const int col = bn + wc + n * 16 + l15;
      const float bc = bias[col];
      if constexpr (OUTMODE == 2) {
        const int sec = col >> 8, hh = (col >> 5) & 7, d = col & 31;
        const int bb = row0 >> 9, nr0 = row0 & 511;
        bf16* dst = (bf16*)Cout + (size_t)sec * QHSZ +
                    (((size_t)bb * 8 + hh) * 512 + nr0) * 32 + d;
#pragma unroll
        for (int i = 0; i < 4; ++i)
          dst[i * 32] = (bf16)(acc[m][n][i] + bc);
      } else {
#pragma unroll
        for (int i = 0; i < 4; ++i) {
          const size_t idx = (size_t)(row0 + i) * N + col;
          float v = acc[m][n][i] + bc;
          if (RESID) v += (float)resid[idx];
          if (RELU) v = fmaxf(v, 0.f);
          if (OUTMODE == 1) ((bf16*)Cout)[idx] = (bf16)v;
          else              ((float*)Cout)[idx] = v;
        }
      }
    }
  }
}

// ---------------- fused FFN: tmpf = x@W1 relu @ W2 + b2 + resid(xb), fp32 out ----------------
// 64-row blocks, 4 waves; x-tile staged once (full K=256); h-chunks of 128 via padded LDS;
// weight B-fragments read directly from L2-resident W1t/W2t with 1-step prefetch.
__global__ __launch_bounds__(256, 2) void ffn_k(
    const bf16* __restrict__ xb, const bf16* __restrict__ W1t,
    const float* __restrict__ b1, const bf16* __restrict__ W2t,
    const float* __restrict__ b2, float* __restrict__ tmpf) {
  __shared__ __align__(16) bf16 xs[64][264];   // padded: stride 528B (2-way banks)
  __shared__ __align__(16) bf16 hs[64][136];   // padded: stride 272B
  const int tid = threadIdx.x;
  const int wave = tid >> 6, lane = tid & 63;
  const int l15 = lane & 15, l4 = lane >> 4;
  const int wg = (blockIdx.x & 7) * 32 + (blockIdx.x >> 3);  // XCD swizzle, grid 256
  const int bm = wg * 64;
  const int wr = (wave >> 1) * 32;        // row quadrant (h and y)
  const int wc1 = (wave & 1) * 64;        // h col quadrant
  const int wc2 = (wave & 1) * 128;       // y col quadrant

  // ---- stage x tile [64][256] to padded LDS ----
  {
    const int r = tid >> 2, c0 = (tid & 3) * 64;
    const bf16* srcp = xb + (size_t)(bm + r) * 256 + c0;
#pragma unroll
    for (int j = 0; j < 8; ++j)
      *(v8bf*)&xs[r][c0 + j * 8] = *(const v8bf*)(srcp + j * 8);
  }
  __syncthreads();

  v4f yacc[2][8];
#pragma unroll
  for (int m = 0; m < 2; ++m)
#pragma unroll
    for (int n = 0; n < 8; ++n) yacc[m][n] = (v4f){0.f, 0.f, 0.f, 0.f};

  for (int nc = 0; nc < 8; ++nc) {
    const int nb = nc * 128;
    // ---- GEMM1: hacc[64x128 quadrant] = x @ W1t^T ----
    v4f hacc[2][4];
#pragma unroll
    for (int m = 0; m < 2; ++m)
#pragma unroll
      for (int n = 0; n < 4; ++n) hacc[m][n] = (v4f){0.f, 0.f, 0.f, 0.f};
    {
      const bf16* w1base = W1t + (size_t)(nb + wc1 + l15) * 256 + l4 * 8;
      v8bf bcur[4];
#pragma unroll
      for (int n = 0; n < 4; ++n) bcur[n] = *(const v8bf*)(w1base + (size_t)(n * 16) * 256);
#pragma unroll
      for (int ks = 0; ks < 8; ++ks) {
        v8bf bnext[4];
        if (ks < 7) {
#pragma unroll
          for (int n = 0; n < 4; ++n)
            bnext[n] = *(const v8bf*)(w1base + (size_t)(n * 16) * 256 + (ks + 1) * 32);
        }
        const v8bf a0 = *(const v8bf*)&xs[wr + l15][ks * 32 + l4 * 8];
        const v8bf a1 = *(const v8bf*)&xs[wr + 16 + l15][ks * 32 + l4 * 8];
        __builtin_amdgcn_s_setprio(1);
#pragma unroll
        for (int n = 0; n < 4; ++n) {
          hacc[0][n] = __builtin_amdgcn_mfma_f32_16x16x32_bf16(a0, bcur[n], hacc[0][n], 0, 0, 0);
          hacc[1][n] = __builtin_amdgcn_mfma_f32_16x16x32_bf16(a1, bcur[n], hacc[1][n], 0, 0, 0);
        }
        __builtin_amdgcn_s_setprio(0);
        if (ks < 7) {
#pragma unroll
          for (int n = 0; n < 4; ++n) bcur[n] = bnext[n];
        }
      }
    }
    // ---- h = relu(hacc + b1) -> hs ----
#pragma unroll
    for (int m = 0; m < 2; ++m)
#pragma unroll
      for (int n = 0; n < 4; ++n) {
        const int col = wc1 + n * 16 + l15;
        const float bb = b1[nb + col];
#pragma unroll
        for (int i = 0; i < 4; ++i) {
          float h = hacc[m][n][i] + bb;
          h = fmaxf(h, 0.f);
          hs[wr + m * 16 + l4 * 4 + i][col] = (bf16)h;
        }
      }
    __syncthreads();
    // ---- GEMM2: yacc += h @ W2t^T (K = this 128-chunk) ----
    {
      const bf16* w2base = W2t + (size_t)(wc2 + l15) * 1024 + nb + l4 * 8;
      v8bf bcur[8];
#pragma unroll
      for (int n = 0; n < 8; ++n) bcur[n] = *(const v8bf*)(w2base + (size_t)(n * 16) * 1024);
#pragma unroll
      for (int ks = 0; ks < 4; ++ks) {
        v8bf bnext[8];
        if (ks < 3) {
#pragma unroll
          for (int n = 0; n < 8; ++n)
            bnext[n] = *(const v8bf*)(w2base + (size_t)(n * 16) * 1024 + (ks + 1) * 32);
        }
        const v8bf a0 = *(const v8bf*)&hs[wr + l15][ks * 32 + l4 * 8];
        const v8bf a1 = *(const v8bf*)&hs[wr + 16 + l15][ks * 32 + l4 * 8];
        __builtin_amdgcn_s_setprio(1);
#pragma unroll
        for (int n = 0; n < 8; ++n) {
          yacc[0][n] = __builtin_amdgcn_mfma_f32_16x16x32_bf16(a0, bcur[n], yacc[0][n], 0, 0, 0);
          yacc[1][n] = __builtin_amdgcn_mfma_f32_16x16x32_bf16(a1, bcur[n], yacc[1][n], 0, 0, 0);
        }
        __builtin_amdgcn_s_setprio(0);
        if (ks < 3) {
#pragma unroll
          for (int n = 0; n < 8; ++n) bcur[n] = bnext[n];
        }
      }
    }
    __syncthreads();  // hs reused next chunk
  }

  // ---- epilogue: y + b2 + resid(xb) -> tmpf fp32 ----
#pragma unroll
  for (int m = 0; m < 2; ++m) {
    const int row0 = bm + wr + m * 16 + l4 * 4;
#pragma unroll
    for (int n = 0; n < 8; ++n) {
      const int col = wc2 + n * 16 + l15;
      const float bc = b2[col];
#pragma unroll
      for (int i = 0; i < 4; ++i) {
        const size_t idx = (size_t)(row0 + i) * 256 + col;
        tmpf[idx] = yacc[m][n][i] + bc + (float)xb[idx];
      }
    }
  }
}

// ---------------- fused flash attention, head-major QKV, fixed normalizer, fp16 bias ----------------
#define VTS 520
__global__ __launch_bounds__(512, 2) void attn_k(
    const bf16* __restrict__ qkvh, const f16* __restrict__ biasH,
    bf16* __restrict__ outp) {
  __shared__ u16 Vt[32 * VTS];   // V^T: [d][kc]
  const int tid = threadIdx.x;
  const int wave = tid >> 6, lane = tid & 63;
  const int l31 = lane & 31, hi = lane >> 5;
  const int fid = blockIdx.x;            // [0,512)
  const int xcd = fid & 7, idx = fid >> 3;   // idx [0,64)
  const int b = (xcd << 2) | (idx >> 4);
  const int h = (idx >> 1) & 7;
  const int qhalf = idx & 1;
  const u16* Qh = (const u16*)qkvh + (((size_t)b * 8 + h) * 512) * 32;
  const u16* Kh = Qh + QHSZ;
  const u16* Vh = Qh + 2 * QHSZ;
  const int qb = qhalf * 256 + wave * 32;

  {
    const u16* p0 = Vh + (size_t)tid * 32;
#pragma unroll
    for (int d0 = 0; d0 < 32; d0 += 8) {
      v8us a = *(const v8us*)(p0 + d0);
#pragma unroll
      for (int j = 0; j < 8; ++j)
        Vt[(d0 + j) * VTS + tid] = a[j];
    }
  }
  __syncthreads();

  const u16* qrow = Qh + (size_t)(qb + l31) * 32;
  const v8bf qf0 = *(const v8bf*)(qrow + hi * 8);
  const v8bf qf1 = *(const v8bf*)(qrow + 16 + hi * 8);
  const f16* bpl = biasH + ((size_t)(hi * 512 + qb + l31)) * 4;

  const float SC2 = 0.17677669529663688f * 1.4426950408889634f;
  float lsum = 0.f;
  v16f accO = {0.f,0.f,0.f,0.f,0.f,0.f,0.f,0.f,0.f,0.f,0.f,0.f,0.f,0.f,0.f,0.f};

  v8bf ka0 = *(const v8bf*)(Kh + (size_t)l31 * 32 + hi * 8);
  v8bf ka1 = *(const v8bf*)(Kh + (size_t)l31 * 32 + 16 + hi * 8);
  v4h bb[4];
#pragma unroll
  for (int g = 0; g < 4; ++g) bb[g] = *(const v4h*)(bpl + (size_t)(g * 2) * 2048);

  v16f stC = {0.f,0.f,0.f,0.f,0.f,0.f,0.f,0.f,0.f,0.f,0.f,0.f,0.f,0.f,0.f,0.f};
  stC = __builtin_amdgcn_mfma_f32_32x32x16_bf16(ka0, qf0, stC, 0, 0, 0);
  stC = __builtin_amdgcn_mfma_f32_32x32x16_bf16(ka1, qf1, stC, 0, 0, 0);
  {
    const u16* kn = Kh + (size_t)(32 + l31) * 32;
    ka0 = *(const v8bf*)(kn + hi * 8);
    ka1 = *(const v8bf*)(kn + 16 + hi * 8);
  }

  for (int kb = 0; kb < 16; ++kb) {
    const int kbase = kb * 32;
    v16f stN = {0.f,0.f,0.f,0.f,0.f,0.f,0.f,0.f,0.f,0.f,0.f,0.f,0.f,0.f,0.f,0.f};
    __builtin_amdgcn_s_setprio(1);
    stN = __builtin_amdgcn_mfma_f32_32x32x16_bf16(ka0, qf0, stN, 0, 0, 0);
    stN = __builtin_amdgcn_mfma_f32_32x32x16_bf16(ka1, qf1, stN, 0, 0, 0);
    __builtin_amdgcn_s_setprio(0);

    const u16* kn = Kh + (size_t)(kbase + 64 + l31) * 32;
    const v8bf kn0 = *(const v8bf*)(kn + hi * 8);
    const v8bf kn1 = *(const v8bf*)(kn + 16 + hi * 8);
    v4h bn[4];
#pragma unroll
    for (int g = 0; g < 4; ++g)
      bn[g] = *(const v4h*)(bpl + (size_t)((kb + 1) * 8 + g * 2) * 2048);

    float p[16];
#pragma unroll
    for (int r = 0; r < 16; ++r)
      p[r] = EXP2(fmaf(stC[r], SC2, (float)bb[r >> 2][r & 3]));

    float s8[8], s4[4];
#pragma unroll
    for (int r = 0; r < 8; ++r) s8[r] = p[r] + p[r + 8];
#pragma unroll
    for (int r = 0; r < 4; ++r) s4[r] = s8[r] + s8[r + 4];
    lsum += (s4[0] + s4[2]) + (s4[1] + s4[3]);

    unsigned u[8];
#pragma unroll
    for (int t = 0; t < 8; ++t) u[t] = pk_bf16(p[2 * t], p[2 * t + 1]);
    PLSWAP(u[0], u[2]);
    PLSWAP(u[1], u[3]);
    PLSWAP(u[4], u[6]);
    PLSWAP(u[5], u[7]);
    union { v4u u; v8bf h; } cv0, cv1;
    cv0.u = (v4u){u[0], u[1], u[2], u[3]};
    cv1.u = (v4u){u[4], u[5], u[6], u[7]};

    const v8bf va0 = *(const v8bf*)&Vt[l31 * VTS + kbase + hi * 8];
    const v8bf va1 = *(const v8bf*)&Vt[l31 * VTS + kbase + 16 + hi * 8];
    __builtin_amdgcn_s_setprio(1);
    accO = __builtin_amdgcn_mfma_f32_32x32x16_bf16(va0, cv0.h, accO, 0, 0, 0);
    accO = __builtin_amdgcn_mfma_f32_32x32x16_bf16(va1, cv1.h, accO, 0, 0, 0);
    __builtin_amdgcn_s_setprio(0);

    stC = stN;
    ka0 = kn0; ka1 = kn1;
#pragma unroll
    for (int g = 0; g < 4; ++g) bb[g] = bn[g];
  }

  lsum += __shfl_xor(lsum, 32);

  const float inv = 1.0f / lsum;
  u16* orow = (u16*)outp + (size_t)(b * N_ + qb + l31) * D_ + h * 32 + 4 * hi;
#pragma unroll
  for (int g = 0; g < 4; ++g) {
    uint2 w;
    w.x = pk_bf16(accO[4 * g] * inv, accO[4 * g + 1] * inv);
    w.y = pk_bf16(accO[4 * g + 2] * inv, accO[4 * g + 3] * inv);
    *(uint2*)(orow + 8 * g) = w;
  }
}

// ---------------- LayerNorm: fp32 in; MODE 0 -> xb bf16 out, MODE 1 -> fp32 out ----------------
template <int MODE>
__global__ __launch_bounds__(256) void ln_kernel(
    const float* __restrict__ xin,
    const float* __restrict__ g, const float* __restrict__ b,
    float* __restrict__ xout_f32, bf16* __restrict__ xbout) {
  const int wv = threadIdx.x >> 6, ln = threadIdx.x & 63;
  const size_t row = blockIdx.x * 4 + wv;
  const size_t o4 = row * D_ + ln * 4;
  const float4 v = *(const float4*)&xin[o4];
  float s  = (v.x + v.y) + (v.z + v.w);
  float ss = (v.x * v.x + v.y * v.y) + (v.z * v.z + v.w * v.w);
#pragma unroll
  for (int off = 1; off < 64; off <<= 1) {
    s  += __shfl_xor(s, off);
    ss += __shfl_xor(ss, off);
  }
  const float mu = s * (1.f / D_);
  const float var = ss * (1.f / D_) - mu * mu;
  const float rs = rsqrtf(var + 1e-5f);
  const float4 gg = *(const float4*)&g[ln * 4];
  const float4 bb = *(const float4*)&b[ln * 4];
  float4 o;
  o.x = (v.x - mu) * rs * gg.x + bb.x;
  o.y = (v.y - mu) * rs * gg.y + bb.y;
  o.z = (v.z - mu) * rs * gg.z + bb.z;
  o.w = (v.w - mu) * rs * gg.w + bb.w;
  if constexpr (MODE == 1) {
    *(float4*)&xout_f32[o4] = o;
  } else {
    uint2 w;
    w.x = pk_bf16(o.x, o.y);
    w.y = pk_bf16(o.z, o.w);
    *(uint2*)&xbout[o4] = w;
  }
}

extern "C" void kernel_launch(void* const* d_in, const int* in_sizes, int n_in,
                              void* d_out, int out_size, void* d_ws, size_t ws_size,
                              hipStream_t stream) {
  const float* src = (const float*)d_in[0];
  const float* e1  = (const float*)d_in[1];
  const float* e2  = (const float*)d_in[2];
  const float* Wq  = (const float*)d_in[3];
  const float* bq  = (const float*)d_in[4];
  const float* Wk  = (const float*)d_in[5];
  const float* bk  = (const float*)d_in[6];
  const float* Wv  = (const float*)d_in[7];
  const float* bv  = (const float*)d_in[8];
  const float* Wo  = (const float*)d_in[9];
  const float* bo  = (const float*)d_in[10];
  const float* W1  = (const float*)d_in[11];
  const float* b1  = (const float*)d_in[12];
  const float* W2  = (const float*)d_in[13];
  const float* b2  = (const float*)d_in[14];
  const float* g1  = (const float*)d_in[15];
  const float* be1 = (const float*)d_in[16];
  const float* g2  = (const float*)d_in[17];
  const float* be2 = (const float*)d_in[18];

  char* ws = (char*)d_ws;
  size_t off = 0;
  auto alloc = [&](size_t bytes) {
    void* p = ws + off;
    off += (bytes + 255) & ~(size_t)255;
    return p;
  };
  float*    biasP  = (float*)alloc((size_t)1024 * 1024 + 4096);  // fp32, pre-subtraction
  f16*      biasH  = (f16*)  alloc((size_t)2 * 1024 * 1024);     // fp16, 0.52MB used + prefetch pad
  unsigned* mqe    = (unsigned*)alloc((size_t)N_ * 4);
  bf16*     xb     = (bf16*) alloc((size_t)ROWS * D_ * 2);
  bf16*     attn_o = (bf16*) alloc((size_t)ROWS * D_ * 2);
  float*    tmpf   = (float*)alloc((size_t)ROWS * D_ * 4);
  bf16*     qkvh   = (bf16*) alloc((size_t)ROWS * 768 * 2 + 65536);  // head-major qkv
  bf16*     Wqkvt  = (bf16*) alloc((size_t)L_ * 768 * 256 * 2);
  bf16*     Wot    = (bf16*) alloc((size_t)L_ * 256 * 256 * 2);
  bf16*     W1t    = (bf16*) alloc((size_t)L_ * 1024 * 256 * 2);
  bf16*     W2t    = (bf16*) alloc((size_t)L_ * 256 * 1024 * 2);
  float*    bqkv   = (float*)alloc((size_t)L_ * 768 * 4);

  hipMemsetAsync(mqe, 0, (size_t)N_ * 4, stream);
  // biasT[k][q] = e2[k] . e1[q]  -> eK = e2, eQ = e1
  bias_gemm<<<dim3(16, 16), dim3(16, 16), 0, stream>>>(e2, e1, biasP, mqe);
  setup_all<<<7436, 256, 0, stream>>>(
      src, xb, bq, bk, bv, bqkv,
      Wq, Wk, Wv, Wo, W1, W2, Wqkvt, Wot, W1t, W2t, biasP, biasH, mqe);

  for (int l = 0; l < L_; ++l) {
    // QKV: M=16384, N=768, K=256; 128x128, head-major output
    gemm_bf16k<128, 128, 3, 0, 2, 0><<<768, 256, 0, stream>>>(
        xb, Wqkvt + (size_t)l * 196608, bqkv + l * 768, nullptr, qkvh,
        ROWS, 768, 256, 6);
    attn_k<<<512, 512, 0, stream>>>(qkvh, biasH, attn_o);
    // Wo + residual(xb): 64x128, fp32 tmpf out
    gemm_bf16k<64, 128, 4, 0, 0, 1><<<512, 256, 0, stream>>>(
        attn_o, Wot + (size_t)l * 65536, bo + l * 256, xb, tmpf,
        ROWS, 256, 256, 2);
    ln_kernel<0><<<ROWS / 4, 256, 0, stream>>>(tmpf, g1 + l * 256, be1 + l * 256, nullptr, xb);
    // fused FFN: tmpf = relu(xb@W1+b1)@W2 + b2 + xb
    ffn_k<<<256, 256, 0, stream>>>(
        xb, W1t + (size_t)l * 262144, b1 + l * 1024,
        W2t + (size_t)l * 262144, b2 + l * 256, tmpf);
    if (l == L_ - 1)
      ln_kernel<1><<<ROWS / 4, 256, 0, stream>>>(tmpf, g2 + l * 256, be2 + l * 256, (float*)d_out, nullptr);
    else
      ln_kernel<0><<<ROWS / 4, 256, 0, stream>>>(tmpf, g2 + l * 256, be2 + l * 256, nullptr, xb);
  }
}

// Round 17
// 431.893 us; speedup vs baseline: 1.3896x; 1.3896x over previous
//
#include <hip/hip_runtime.h>

typedef __bf16 bf16;
typedef __bf16 v4bf __attribute__((ext_vector_type(4)));
typedef __bf16 v8bf __attribute__((ext_vector_type(8)));
typedef float  v4f  __attribute__((ext_vector_type(4)));
typedef float  v16f __attribute__((ext_vector_type(16)));
typedef unsigned short u16;
typedef u16 v8us __attribute__((ext_vector_type(8)));
typedef unsigned int v4u __attribute__((ext_vector_type(4)));
typedef _Float16 f16;
typedef f16 v4h __attribute__((ext_vector_type(4)));

#define L_ 4
#define B_ 32
#define N_ 512
#define D_ 256
#define H_ 8
#define F_ 1024
#define ROWS (B_*N_)               // 16384
#define QHSZ ((size_t)B_*H_*N_*32) // elems per Q/K/V head-major section

__device__ __forceinline__ void gload16(const void* g, void* l) {
  __builtin_amdgcn_global_load_lds((__attribute__((address_space(1))) void*)g,
                                   (__attribute__((address_space(3))) void*)l,
                                   16, 0, 0);
}

__device__ __forceinline__ unsigned pk_bf16(float a, float b) {
  unsigned r;
  asm("v_cvt_pk_bf16_f32 %0, %1, %2" : "=v"(r) : "v"(a), "v"(b));
  return r;
}

// swap: a.hi <-> b.lo
#define PLSWAP(a, b) asm volatile("v_permlane32_swap_b32 %0, %1" : "+v"(a), "+v"(b))

#define EXP2(x) __builtin_amdgcn_exp2f(x)

// monotone float<->uint encoding for atomicMax
__device__ __forceinline__ unsigned encf(float f) {
  unsigned u = __float_as_uint(f);
  return (u & 0x80000000u) ? ~u : (u | 0x80000000u);
}
__device__ __forceinline__ float decf(unsigned e) {
  unsigned b = (e & 0x80000000u) ? (e & 0x7fffffffu) : ~e;
  return __uint_as_float(b);
}

template <int N> __device__ __forceinline__ void waitvm() {
  if constexpr (N == 0) asm volatile("s_waitcnt vmcnt(0)" ::: "memory");
  else if constexpr (N == 2) asm volatile("s_waitcnt vmcnt(2)" ::: "memory");
  else if constexpr (N == 3) asm volatile("s_waitcnt vmcnt(3)" ::: "memory");
  else if constexpr (N == 4) asm volatile("s_waitcnt vmcnt(4)" ::: "memory");
  else if constexpr (N == 5) asm volatile("s_waitcnt vmcnt(5)" ::: "memory");
  else if constexpr (N == 6) asm volatile("s_waitcnt vmcnt(6)" ::: "memory");
}

// ---------------- biasP (permuted, MFMA C-layout) = (eK @ eQ^T) * log2e; also mq = colmax ----------------
// biasT[k][q] = eK[k] . eQ[q]  (called with eK = e2, eQ = e1)
// 32x32 tile, 2x2 per thread; grid 16x16 = 256 blocks (full machine)
__global__ __launch_bounds__(256) void bias_gemm(
    const float* __restrict__ eK, const float* __restrict__ eQ,
    float* __restrict__ biasP, unsigned* __restrict__ mqe) {
  __shared__ float As[32][17];   // eK rows (k)
  __shared__ float Bs[32][17];   // eQ rows (q)
  __shared__ float pm[16][32];
  const int tx = threadIdx.x, ty = threadIdx.y;     // 16x16
  const int t = ty * 16 + tx;
  const int lrow = t >> 3, lkq = (t & 7) * 2;
  const int r0 = blockIdx.y * 32, c0 = blockIdx.x * 32;
  float acc[2][2] = {{0.f, 0.f}, {0.f, 0.f}};
  for (int k0 = 0; k0 < D_; k0 += 16) {
    const float2 a2 = *(const float2*)&eK[(size_t)(r0 + lrow) * D_ + k0 + lkq];
    const float2 b2 = *(const float2*)&eQ[(size_t)(c0 + lrow) * D_ + k0 + lkq];
    As[lrow][lkq] = a2.x; As[lrow][lkq + 1] = a2.y;
    Bs[lrow][lkq] = b2.x; Bs[lrow][lkq + 1] = b2.y;
    __syncthreads();
#pragma unroll
    for (int k = 0; k < 16; ++k) {
      const float a0 = As[ty * 2][k], a1 = As[ty * 2 + 1][k];
      const float b0 = Bs[tx * 2][k], b1 = Bs[tx * 2 + 1][k];
      acc[0][0] += a0 * b0; acc[0][1] += a0 * b1;
      acc[1][0] += a1 * b0; acc[1][1] += a1 * b1;
    }
    __syncthreads();
  }
#pragma unroll
  for (int i = 0; i < 2; ++i)
#pragma unroll
    for (int j = 0; j < 2; ++j) acc[i][j] *= 1.4426950408889634f;
  // permuted write: row gr = k-index, col q
#pragma unroll
  for (int i = 0; i < 2; ++i) {
    const int gr = r0 + ty * 2 + i;
    const int kb = gr >> 5, r5 = gr & 31;
    const int blk = kb * 8 + (r5 >> 3) * 2 + ((r5 >> 2) & 1);
#pragma unroll
    for (int j = 0; j < 2; ++j) {
      const int q = c0 + tx * 2 + j;
      biasP[(size_t)(blk * 512 + q) * 4 + (r5 & 3)] = acc[i][j];
    }
  }
  // block-local column max -> atomics
  pm[ty][tx * 2]     = fmaxf(acc[0][0], acc[1][0]);
  pm[ty][tx * 2 + 1] = fmaxf(acc[0][1], acc[1][1]);
  __syncthreads();
  if (ty == 0) {
#pragma unroll
    for (int j = 0; j < 2; ++j) {
      float m = pm[0][tx * 2 + j];
#pragma unroll
      for (int y = 1; y < 16; ++y) m = fmaxf(m, pm[y][tx * 2 + j]);
      atomicMax(&mqe[c0 + tx * 2 + j], encf(m));
    }
  }
}

// ---------------- unified setup: init_x + pack_bqkv + all weight transposes + subm->fp16 ----------------
__device__ __forceinline__ void convT_tile(
    const float* __restrict__ W, bf16* __restrict__ Wt,
    int K, int N, size_t inL, size_t outL, int l, int k0, int n0, int tid,
    float (*t)[33]) {
  const int r = tid >> 5, c = tid & 31;
#pragma unroll
  for (int i = 0; i < 4; ++i)
    t[r + 8 * i][c] = W[l * inL + (size_t)(k0 + r + 8 * i) * N + n0 + c];
  __syncthreads();
#pragma unroll
  for (int i = 0; i < 4; ++i)
    Wt[l * outL + (size_t)(n0 + r + 8 * i) * K + k0 + c] = (bf16)t[c][r + 8 * i];
}

// blocks: [0,4096) init_x | [4096,4108) pack_bqkv | [4108,5132) Wq/Wk/Wv/Wo |
//         [5132,6156) W1 | [6156,7180) W2 | [7180,7436) subm: biasH = f16(biasP - mq)
__global__ __launch_bounds__(256) void setup_all(
    const float* __restrict__ src, bf16* __restrict__ xb,
    const float* __restrict__ bq, const float* __restrict__ bk,
    const float* __restrict__ bv, float* __restrict__ bqkv,
    const float* __restrict__ Wq, const float* __restrict__ Wk,
    const float* __restrict__ Wv, const float* __restrict__ Wo,
    const float* __restrict__ W1, const float* __restrict__ W2,
    bf16* __restrict__ Wqkvt, bf16* __restrict__ Wot,
    bf16* __restrict__ W1t, bf16* __restrict__ W2t,
    const float* __restrict__ biasP, f16* __restrict__ biasH,
    const unsigned* __restrict__ mqe) {
  __shared__ float t[32][33];
  const int tid = threadIdx.x;
  int id = blockIdx.x;
  if (id < 4096) {
    const int i = id * 256 + tid;  // float4 index
    float4 v = ((const float4*)src)[i];
    uint2 w;
    w.x = pk_bf16(v.x, v.y);
    w.y = pk_bf16(v.z, v.w);
    ((uint2*)xb)[i] = w;
    return;
  }
  id -= 4096;
  if (id < 12) {
    const int i = id * 256 + tid;
    if (i < L_ * 768) {
      const int l = i / 768, n = i - l * 768;
      float v = (n < 256) ? bq[l * 256 + n]
              : (n < 512) ? bk[l * 256 + n - 256]
                          : bv[l * 256 + n - 512];
      bqkv[i] = v;
    }
    return;
  }
  id -= 12;
  if (id < 1024) {
    const int w = id >> 8, tt = id & 255;
    const int l = tt >> 6, tile = tt & 63;
    const int n0 = (tile & 7) * 32, k0 = (tile >> 3) * 32;
    const float* W = (w == 0) ? Wq : (w == 1) ? Wk : (w == 2) ? Wv : Wo;
    bf16* Wt = (w == 3) ? Wot : (Wqkvt + w * 65536);
    const size_t outL = (w == 3) ? 65536 : 196608;
    convT_tile(W, Wt, 256, 256, 65536, outL, l, k0, n0, tid, t);
    return;
  }
  id -= 1024;
  if (id < 1024) {
    const int l = id >> 8, tile = id & 255;
    const int n0 = (tile & 31) * 32, k0 = (tile >> 5) * 32;
    convT_tile(W1, W1t, 256, 1024, 262144, 262144, l, k0, n0, tid, t);
    return;
  }
  id -= 1024;
  if (id < 1024) {
    const int l = id >> 8, tile = id & 255;
    const int n0 = (tile & 7) * 32, k0 = (tile >> 3) * 32;
    convT_tile(W2, W2t, 1024, 256, 262144, 262144, l, k0, n0, tid, t);
    return;
  }
  id -= 1024;
  {
    const int i = id * 256 + tid;  // 65536 float4
    const float4 v = ((const float4*)biasP)[i];
    const float m = decf(mqe[i & 511]);
    v4h o;
    o[0] = (f16)(v.x - m); o[1] = (f16)(v.y - m);
    o[2] = (f16)(v.z - m); o[3] = (f16)(v.w - m);
    *(v4h*)&biasH[(size_t)i * 4] = o;
  }
}

// ---------------- bf16 MFMA GEMM, 2-phase pipelined, XCD-swizzled ----------------
// OUTMODE: 0 = fp32 row-major, 1 = bf16 row-major, 2 = bf16 head-major QKV (N=768)
template <int BM, int BN, int WPC, int RELU, int OUTMODE, int RESID>
__global__ __launch_bounds__(256, WPC) void gemm_bf16k(
    const bf16* __restrict__ A, const bf16* __restrict__ Bt,
    const float* __restrict__ bias, const bf16* __restrict__ resid,
    void* __restrict__ Cout, int M, int N, int K, int nbx) {
  constexpr int MR = BM / 32, NR = BN / 32;
  constexpr int NSLAB = (BM + BN) / 16;
  constexpr int LPW = NSLAB / 4;
  constexpr int BUFE = (BM + BN) * 32;
  __shared__ __align__(16) bf16 lds[3 * BUFE];
  const int tid  = threadIdx.x;
  const int wave = tid >> 6, lane = tid & 63;
  const int l15 = lane & 15, l4 = lane >> 4;
  const int qq = gridDim.x >> 3;
  const int wg = (blockIdx.x & 7) * qq + (blockIdx.x >> 3);
  const int bx = wg % nbx, by = wg / nbx;
  const int bm = by * BM, bn = bx * BN;
  const int wr = (wave >> 1) * (BM / 2), wc = (wave & 1) * (BN / 2);
  const int lrow = lane >> 2;
  const int lk   = (lane & 3) * 8;

  v4f acc[MR][NR];
#pragma unroll
  for (int m = 0; m < MR; ++m)
#pragma unroll
    for (int n = 0; n < NR; ++n) acc[m][n] = (v4f){0.f, 0.f, 0.f, 0.f};

  auto STAGE = [&](int buf, int k0) {
    bf16* dst = &lds[buf * BUFE];
#pragma unroll
    for (int s = wave; s < NSLAB; s += 4) {
      if (s < BM / 16)
        gload16(A + (size_t)(bm + s * 16 + lrow) * K + k0 + lk, dst + s * 512);
      else
        gload16(Bt + (size_t)(bn + (s - BM / 16) * 16 + lrow) * K + k0 + lk, dst + s * 512);
    }
  };

  const int nk = K >> 5;
  STAGE(0, 0);
  STAGE(1, 32);
  waitvm<LPW>();
  __builtin_amdgcn_s_barrier();
  __builtin_amdgcn_sched_barrier(0);

  int cur = 0;
  for (int t = 0; t < nk; ++t) {
    const bool pf = (t + 2 < nk);
    if (pf) STAGE(cur == 0 ? 2 : cur - 1, (t + 2) * 32);
    const bf16* buf = &lds[cur * BUFE];
    v8bf af[MR], bfr[NR];
#pragma unroll
    for (int m = 0; m < MR; ++m)
      af[m] = *(const v8bf*)&buf[(wr + m * 16 + l15) * 32 + l4 * 8];
#pragma unroll
    for (int n = 0; n < NR; ++n)
      bfr[n] = *(const v8bf*)&buf[BM * 32 + (wc + n * 16 + l15) * 32 + l4 * 8];
    __builtin_amdgcn_s_setprio(1);
#pragma unroll
    for (int m = 0; m < MR; ++m)
#pragma unroll
      for (int n = 0; n < NR; ++n)
        acc[m][n] = __builtin_amdgcn_mfma_f32_16x16x32_bf16(af[m], bfr[n], acc[m][n], 0, 0, 0);
    __builtin_amdgcn_s_setprio(0);
    if (pf) waitvm<LPW>();
    else    waitvm<0>();
    __builtin_amdgcn_s_barrier();
    __builtin_amdgcn_sched_barrier(0);
    cur = (cur == 2) ? 0 : cur + 1;
  }

#pragma unroll
  for (int m = 0; m < MR; ++m) {
    const int row0 = bm + wr + m * 16 + l4 * 4;
#pragma unroll
    for (int n = 0; n < NR; ++n) {
      const int col = bn + wc + n * 16 + l15;
      const float bc = bias[col];
      if constexpr (OUTMODE == 2) {
        // head-major QKV: sec (q/k/v), head, d
        const int sec = col >> 8, hh = (col >> 5) & 7, d = col & 31;
        const int bb = row0 >> 9, nr0 = row0 & 511;
        bf16* dst = (bf16*)Cout + (size_t)sec * QHSZ +
                    (((size_t)bb * 8 + hh) * 512 + nr0) * 32 + d;
#pragma unroll
        for (int i = 0; i < 4; ++i)
          dst[i * 32] = (bf16)(acc[m][n][i] + bc);
      } else {
#pragma unroll
        for (int i = 0; i < 4; ++i) {
          const size_t idx = (size_t)(row0 + i) * N + col;
          float v = acc[m][n][i] + bc;
          if (RESID) v += (float)resid[idx];
          if (RELU) v = fmaxf(v, 0.f);
          if (OUTMODE == 1) ((bf16*)Cout)[idx] = (bf16)v;
          else              ((float*)Cout)[idx] = v;
        }
      }
    }
  }
}

// ---------------- fused flash attention, head-major QKV, fixed normalizer, fp16 bias ----------------
// 512 threads / 8 waves; 2 blocks per (b,h) (256 q-rows each); grid 512 = 2 blocks/CU
#define VTS 520
__global__ __launch_bounds__(512, 2) void attn_k(
    const bf16* __restrict__ qkvh, const f16* __restrict__ biasH,
    bf16* __restrict__ outp) {
  __shared__ u16 Vt[32 * VTS];   // V^T: [d][kc]
  const int tid = threadIdx.x;
  const int wave = tid >> 6, lane = tid & 63;
  const int l31 = lane & 31, hi = lane >> 5;
  const int fid = blockIdx.x;            // [0,512)
  const int xcd = fid & 7, idx = fid >> 3;   // idx [0,64)
  const int b = (xcd << 2) | (idx >> 4);
  const int h = (idx >> 1) & 7;
  const int qhalf = idx & 1;
  const u16* Qh = (const u16*)qkvh + (((size_t)b * 8 + h) * 512) * 32;
  const u16* Kh = Qh + QHSZ;
  const u16* Vh = Qh + 2 * QHSZ;
  const int qb = qhalf * 256 + wave * 32;

  // ---- stage V^T (once per block): thread t packs row t (contiguous stream) ----
  {
    const u16* p0 = Vh + (size_t)tid * 32;
#pragma unroll
    for (int d0 = 0; d0 < 32; d0 += 8) {
      v8us a = *(const v8us*)(p0 + d0);
#pragma unroll
      for (int j = 0; j < 8; ++j)
        Vt[(d0 + j) * VTS + tid] = a[j];
    }
  }
  __syncthreads();

  // ---- Q fragments (B operand), held all chunks ----
  const u16* qrow = Qh + (size_t)(qb + l31) * 32;
  const v8bf qf0 = *(const v8bf*)(qrow + hi * 8);
  const v8bf qf1 = *(const v8bf*)(qrow + 16 + hi * 8);
  const f16* bpl = biasH + ((size_t)(hi * 512 + qb + l31)) * 4;

  const float SC2 = 0.17677669529663688f * 1.4426950408889634f;
  float lsum = 0.f;
  v16f accO = {0.f,0.f,0.f,0.f,0.f,0.f,0.f,0.f,0.f,0.f,0.f,0.f,0.f,0.f,0.f,0.f};

  v8bf ka0 = *(const v8bf*)(Kh + (size_t)l31 * 32 + hi * 8);
  v8bf ka1 = *(const v8bf*)(Kh + (size_t)l31 * 32 + 16 + hi * 8);
  v4h bb[4];
#pragma unroll
  for (int g = 0; g < 4; ++g) bb[g] = *(const v4h*)(bpl + (size_t)(g * 2) * 2048);

  v16f stC = {0.f,0.f,0.f,0.f,0.f,0.f,0.f,0.f,0.f,0.f,0.f,0.f,0.f,0.f,0.f,0.f};
  stC = __builtin_amdgcn_mfma_f32_32x32x16_bf16(ka0, qf0, stC, 0, 0, 0);
  stC = __builtin_amdgcn_mfma_f32_32x32x16_bf16(ka1, qf1, stC, 0, 0, 0);
  {
    const u16* kn = Kh + (size_t)(32 + l31) * 32;
    ka0 = *(const v8bf*)(kn + hi * 8);
    ka1 = *(const v8bf*)(kn + 16 + hi * 8);
  }

  for (int kb = 0; kb < 16; ++kb) {
    const int kbase = kb * 32;
    // QK^T(kb+1) early: matrix pipe runs under softmax VALU of chunk kb
    v16f stN = {0.f,0.f,0.f,0.f,0.f,0.f,0.f,0.f,0.f,0.f,0.f,0.f,0.f,0.f,0.f,0.f};
    __builtin_amdgcn_s_setprio(1);
    stN = __builtin_amdgcn_mfma_f32_32x32x16_bf16(ka0, qf0, stN, 0, 0, 0);
    stN = __builtin_amdgcn_mfma_f32_32x32x16_bf16(ka1, qf1, stN, 0, 0, 0);
    __builtin_amdgcn_s_setprio(0);

    // prefetch K(kb+2) and bias(kb+1)  (unconditional; reads spill into padded region = valid)
    const u16* kn = Kh + (size_t)(kbase + 64 + l31) * 32;
    const v8bf kn0 = *(const v8bf*)(kn + hi * 8);
    const v8bf kn1 = *(const v8bf*)(kn + 16 + hi * 8);
    v4h bn[4];
#pragma unroll
    for (int g = 0; g < 4; ++g)
      bn[g] = *(const v4h*)(bpl + (size_t)((kb + 1) * 8 + g * 2) * 2048);

    float p[16];
#pragma unroll
    for (int r = 0; r < 16; ++r)
      p[r] = EXP2(fmaf(stC[r], SC2, (float)bb[r >> 2][r & 3]));

    float s8[8], s4[4];
#pragma unroll
    for (int r = 0; r < 8; ++r) s8[r] = p[r] + p[r + 8];
#pragma unroll
    for (int r = 0; r < 4; ++r) s4[r] = s8[r] + s8[r + 4];
    lsum += (s4[0] + s4[2]) + (s4[1] + s4[3]);

    unsigned u[8];
#pragma unroll
    for (int t = 0; t < 8; ++t) u[t] = pk_bf16(p[2 * t], p[2 * t + 1]);
    PLSWAP(u[0], u[2]);
    PLSWAP(u[1], u[3]);
    PLSWAP(u[4], u[6]);
    PLSWAP(u[5], u[7]);
    union { v4u u; v8bf h; } cv0, cv1;
    cv0.u = (v4u){u[0], u[1], u[2], u[3]};
    cv1.u = (v4u){u[4], u[5], u[6], u[7]};

    const v8bf va0 = *(const v8bf*)&Vt[l31 * VTS + kbase + hi * 8];
    const v8bf va1 = *(const v8bf*)&Vt[l31 * VTS + kbase + 16 + hi * 8];
    __builtin_amdgcn_s_setprio(1);
    accO = __builtin_amdgcn_mfma_f32_32x32x16_bf16(va0, cv0.h, accO, 0, 0, 0);
    accO = __builtin_amdgcn_mfma_f32_32x32x16_bf16(va1, cv1.h, accO, 0, 0, 0);
    __builtin_amdgcn_s_setprio(0);

    stC = stN;
    ka0 = kn0; ka1 = kn1;
#pragma unroll
    for (int g = 0; g < 4; ++g) bb[g] = bn[g];
  }

  lsum += __shfl_xor(lsum, 32);

  const float inv = 1.0f / lsum;
  u16* orow = (u16*)outp + (size_t)(b * N_ + qb + l31) * D_ + h * 32 + 4 * hi;
#pragma unroll
  for (int g = 0; g < 4; ++g) {
    uint2 w;
    w.x = pk_bf16(accO[4 * g] * inv, accO[4 * g + 1] * inv);
    w.y = pk_bf16(accO[4 * g + 2] * inv, accO[4 * g + 3] * inv);
    *(uint2*)(orow + 8 * g) = w;
  }
}

// ---------------- LayerNorm: fp32 in; MODE 0 -> xb bf16 out, MODE 1 -> fp32 out ----------------
template <int MODE>
__global__ __launch_bounds__(256) void ln_kernel(
    const float* __restrict__ xin,
    const float* __restrict__ g, const float* __restrict__ b,
    float* __restrict__ xout_f32, bf16* __restrict__ xbout) {
  const int wv = threadIdx.x >> 6, ln = threadIdx.x & 63;
  const size_t row = blockIdx.x * 4 + wv;
  const size_t o4 = row * D_ + ln * 4;
  const float4 v = *(const float4*)&xin[o4];
  float s  = (v.x + v.y) + (v.z + v.w);
  float ss = (v.x * v.x + v.y * v.y) + (v.z * v.z + v.w * v.w);
#pragma unroll
  for (int off = 1; off < 64; off <<= 1) {
    s  += __shfl_xor(s, off);
    ss += __shfl_xor(ss, off);
  }
  const float mu = s * (1.f / D_);
  const float var = ss * (1.f / D_) - mu * mu;
  const float rs = rsqrtf(var + 1e-5f);
  const float4 gg = *(const float4*)&g[ln * 4];
  const float4 bb = *(const float4*)&b[ln * 4];
  float4 o;
  o.x = (v.x - mu) * rs * gg.x + bb.x;
  o.y = (v.y - mu) * rs * gg.y + bb.y;
  o.z = (v.z - mu) * rs * gg.z + bb.z;
  o.w = (v.w - mu) * rs * gg.w + bb.w;
  if constexpr (MODE == 1) {
    *(float4*)&xout_f32[o4] = o;
  } else {
    uint2 w;
    w.x = pk_bf16(o.x, o.y);
    w.y = pk_bf16(o.z, o.w);
    *(uint2*)&xbout[o4] = w;
  }
}

extern "C" void kernel_launch(void* const* d_in, const int* in_sizes, int n_in,
                              void* d_out, int out_size, void* d_ws, size_t ws_size,
                              hipStream_t stream) {
  const float* src = (const float*)d_in[0];
  const float* e1  = (const float*)d_in[1];
  const float* e2  = (const float*)d_in[2];
  const float* Wq  = (const float*)d_in[3];
  const float* bq  = (const float*)d_in[4];
  const float* Wk  = (const float*)d_in[5];
  const float* bk  = (const float*)d_in[6];
  const float* Wv  = (const float*)d_in[7];
  const float* bv  = (const float*)d_in[8];
  const float* Wo  = (const float*)d_in[9];
  const float* bo  = (const float*)d_in[10];
  const float* W1  = (const float*)d_in[11];
  const float* b1  = (const float*)d_in[12];
  const float* W2  = (const float*)d_in[13];
  const float* b2  = (const float*)d_in[14];
  const float* g1  = (const float*)d_in[15];
  const float* be1 = (const float*)d_in[16];
  const float* g2  = (const float*)d_in[17];
  const float* be2 = (const float*)d_in[18];

  char* ws = (char*)d_ws;
  size_t off = 0;
  auto alloc = [&](size_t bytes) {
    void* p = ws + off;
    off += (bytes + 255) & ~(size_t)255;
    return p;
  };
  float*    biasP  = (float*)alloc((size_t)1024 * 1024 + 4096);  // fp32, pre-subtraction
  f16*      biasH  = (f16*)  alloc((size_t)2 * 1024 * 1024);     // fp16, 0.52MB used + prefetch pad
  unsigned* mqe    = (unsigned*)alloc((size_t)N_ * 4);
  bf16*     xb     = (bf16*) alloc((size_t)ROWS * D_ * 2);
  bf16*     attn_o = (bf16*) alloc((size_t)ROWS * D_ * 2);
  float*    tmpf   = (float*)alloc((size_t)ROWS * D_ * 4);
  bf16*     qkvh   = (bf16*) alloc((size_t)ROWS * 1024 * 2 + 65536);  // shared: head-major qkv / ffn h1
  bf16*     h1     = qkvh;
  bf16*     Wqkvt  = (bf16*) alloc((size_t)L_ * 768 * 256 * 2);
  bf16*     Wot    = (bf16*) alloc((size_t)L_ * 256 * 256 * 2);
  bf16*     W1t    = (bf16*) alloc((size_t)L_ * 1024 * 256 * 2);
  bf16*     W2t    = (bf16*) alloc((size_t)L_ * 256 * 1024 * 2);
  float*    bqkv   = (float*)alloc((size_t)L_ * 768 * 4);

  hipMemsetAsync(mqe, 0, (size_t)N_ * 4, stream);
  // biasT[k][q] = e2[k] . e1[q]  -> eK = e2, eQ = e1
  bias_gemm<<<dim3(16, 16), dim3(16, 16), 0, stream>>>(e2, e1, biasP, mqe);
  setup_all<<<7436, 256, 0, stream>>>(
      src, xb, bq, bk, bv, bqkv,
      Wq, Wk, Wv, Wo, W1, W2, Wqkvt, Wot, W1t, W2t, biasP, biasH, mqe);

  for (int l = 0; l < L_; ++l) {
    // QKV: M=16384, N=768, K=256; 128x128, head-major output
    gemm_bf16k<128, 128, 3, 0, 2, 0><<<768, 256, 0, stream>>>(
        xb, Wqkvt + (size_t)l * 196608, bqkv + l * 768, nullptr, qkvh,
        ROWS, 768, 256, 6);
    attn_k<<<512, 512, 0, stream>>>(qkvh, biasH, attn_o);
    // Wo + residual(xb): 64x128, fp32 tmpf out
    gemm_bf16k<64, 128, 4, 0, 0, 1><<<512, 256, 0, stream>>>(
        attn_o, Wot + (size_t)l * 65536, bo + l * 256, xb, tmpf,
        ROWS, 256, 256, 2);
    ln_kernel<0><<<ROWS / 4, 256, 0, stream>>>(tmpf, g1 + l * 256, be1 + l * 256, nullptr, xb);
    // W1 + ReLU: 128x256 (2/CU, single residency round), bf16 out
    gemm_bf16k<128, 256, 2, 1, 1, 0><<<512, 256, 0, stream>>>(
        xb, W1t + (size_t)l * 262144, b1 + l * 1024, nullptr, h1,
        ROWS, 1024, 256, 4);
    // W2 + residual(xb): 64x128, fp32 tmpf out
    gemm_bf16k<64, 128, 4, 0, 0, 1><<<512, 256, 0, stream>>>(
        h1, W2t + (size_t)l * 262144, b2 + l * 256, xb, tmpf,
        ROWS, 256, 1024, 2);
    if (l == L_ - 1)
      ln_kernel<1><<<ROWS / 4, 256, 0, stream>>>(tmpf, g2 + l * 256, be2 + l * 256, (float*)d_out, nullptr);
    else
      ln_kernel<0><<<ROWS / 4, 256, 0, stream>>>(tmpf, g2 + l * 256, be2 + l * 256, nullptr, xb);
  }
}

// Round 18
// 428.220 us; speedup vs baseline: 1.4015x; 1.0086x over previous
//
#include <hip/hip_runtime.h>

typedef __bf16 bf16;
typedef __bf16 v4bf __attribute__((ext_vector_type(4)));
typedef __bf16 v8bf __attribute__((ext_vector_type(8)));
typedef float  v4f  __attribute__((ext_vector_type(4)));
typedef float  v16f __attribute__((ext_vector_type(16)));
typedef unsigned short u16;
typedef u16 v8us __attribute__((ext_vector_type(8)));
typedef unsigned int v4u __attribute__((ext_vector_type(4)));
typedef _Float16 f16;
typedef f16 v4h __attribute__((ext_vector_type(4)));

#define L_ 4
#define B_ 32
#define N_ 512
#define D_ 256
#define H_ 8
#define F_ 1024
#define ROWS (B_*N_)               // 16384
#define QHSZ ((size_t)B_*H_*N_*32) // elems per Q/K/V head-major section

__device__ __forceinline__ void gload16(const void* g, void* l) {
  __builtin_amdgcn_global_load_lds((__attribute__((address_space(1))) void*)g,
                                   (__attribute__((address_space(3))) void*)l,
                                   16, 0, 0);
}

__device__ __forceinline__ unsigned pk_bf16(float a, float b) {
  unsigned r;
  asm("v_cvt_pk_bf16_f32 %0, %1, %2" : "=v"(r) : "v"(a), "v"(b));
  return r;
}

// swap: a.hi <-> b.lo
#define PLSWAP(a, b) asm volatile("v_permlane32_swap_b32 %0, %1" : "+v"(a), "+v"(b))

#define EXP2(x) __builtin_amdgcn_exp2f(x)

// monotone float<->uint encoding for atomicMax
__device__ __forceinline__ unsigned encf(float f) {
  unsigned u = __float_as_uint(f);
  return (u & 0x80000000u) ? ~u : (u | 0x80000000u);
}
__device__ __forceinline__ float decf(unsigned e) {
  unsigned b = (e & 0x80000000u) ? (e & 0x7fffffffu) : ~e;
  return __uint_as_float(b);
}

template <int N> __device__ __forceinline__ void waitvm() {
  if constexpr (N == 0) asm volatile("s_waitcnt vmcnt(0)" ::: "memory");
  else if constexpr (N == 2) asm volatile("s_waitcnt vmcnt(2)" ::: "memory");
  else if constexpr (N == 3) asm volatile("s_waitcnt vmcnt(3)" ::: "memory");
  else if constexpr (N == 4) asm volatile("s_waitcnt vmcnt(4)" ::: "memory");
  else if constexpr (N == 5) asm volatile("s_waitcnt vmcnt(5)" ::: "memory");
  else if constexpr (N == 6) asm volatile("s_waitcnt vmcnt(6)" ::: "memory");
}

// ---------------- biasP (permuted, MFMA C-layout) = (eK @ eQ^T) * log2e; also mq = colmax ----------------
// biasT[k][q] = eK[k] . eQ[q]  (called with eK = e2, eQ = e1)
// 32x32 tile, 2x2 per thread; grid 16x16 = 256 blocks (full machine)
__global__ __launch_bounds__(256) void bias_gemm(
    const float* __restrict__ eK, const float* __restrict__ eQ,
    float* __restrict__ biasP, unsigned* __restrict__ mqe) {
  __shared__ float As[32][17];   // eK rows (k)
  __shared__ float Bs[32][17];   // eQ rows (q)
  __shared__ float pm[16][32];
  const int tx = threadIdx.x, ty = threadIdx.y;     // 16x16
  const int t = ty * 16 + tx;
  const int lrow = t >> 3, lkq = (t & 7) * 2;
  const int r0 = blockIdx.y * 32, c0 = blockIdx.x * 32;
  float acc[2][2] = {{0.f, 0.f}, {0.f, 0.f}};
  for (int k0 = 0; k0 < D_; k0 += 16) {
    const float2 a2 = *(const float2*)&eK[(size_t)(r0 + lrow) * D_ + k0 + lkq];
    const float2 b2 = *(const float2*)&eQ[(size_t)(c0 + lrow) * D_ + k0 + lkq];
    As[lrow][lkq] = a2.x; As[lrow][lkq + 1] = a2.y;
    Bs[lrow][lkq] = b2.x; Bs[lrow][lkq + 1] = b2.y;
    __syncthreads();
#pragma unroll
    for (int k = 0; k < 16; ++k) {
      const float a0 = As[ty * 2][k], a1 = As[ty * 2 + 1][k];
      const float b0 = Bs[tx * 2][k], b1 = Bs[tx * 2 + 1][k];
      acc[0][0] += a0 * b0; acc[0][1] += a0 * b1;
      acc[1][0] += a1 * b0; acc[1][1] += a1 * b1;
    }
    __syncthreads();
  }
#pragma unroll
  for (int i = 0; i < 2; ++i)
#pragma unroll
    for (int j = 0; j < 2; ++j) acc[i][j] *= 1.4426950408889634f;
  // permuted write: row gr = k-index, col q
#pragma unroll
  for (int i = 0; i < 2; ++i) {
    const int gr = r0 + ty * 2 + i;
    const int kb = gr >> 5, r5 = gr & 31;
    const int blk = kb * 8 + (r5 >> 3) * 2 + ((r5 >> 2) & 1);
#pragma unroll
    for (int j = 0; j < 2; ++j) {
      const int q = c0 + tx * 2 + j;
      biasP[(size_t)(blk * 512 + q) * 4 + (r5 & 3)] = acc[i][j];
    }
  }
  // block-local column max -> atomics
  pm[ty][tx * 2]     = fmaxf(acc[0][0], acc[1][0]);
  pm[ty][tx * 2 + 1] = fmaxf(acc[0][1], acc[1][1]);
  __syncthreads();
  if (ty == 0) {
#pragma unroll
    for (int j = 0; j < 2; ++j) {
      float m = pm[0][tx * 2 + j];
#pragma unroll
      for (int y = 1; y < 16; ++y) m = fmaxf(m, pm[y][tx * 2 + j]);
      atomicMax(&mqe[c0 + tx * 2 + j], encf(m));
    }
  }
}

// ---------------- unified setup: init_x + pack_bqkv + all weight transposes + subm->fp16 ----------------
__device__ __forceinline__ void convT_tile(
    const float* __restrict__ W, bf16* __restrict__ Wt,
    int K, int N, size_t inL, size_t outL, int l, int k0, int n0, int tid,
    float (*t)[33]) {
  const int r = tid >> 5, c = tid & 31;
#pragma unroll
  for (int i = 0; i < 4; ++i)
    t[r + 8 * i][c] = W[l * inL + (size_t)(k0 + r + 8 * i) * N + n0 + c];
  __syncthreads();
#pragma unroll
  for (int i = 0; i < 4; ++i)
    Wt[l * outL + (size_t)(n0 + r + 8 * i) * K + k0 + c] = (bf16)t[c][r + 8 * i];
}

// blocks: [0,4096) init_x | [4096,4108) pack_bqkv | [4108,5132) Wq/Wk/Wv/Wo |
//         [5132,6156) W1 | [6156,7180) W2 | [7180,7436) subm: biasH = f16(biasP - mq)
__global__ __launch_bounds__(256) void setup_all(
    const float* __restrict__ src, bf16* __restrict__ xb,
    const float* __restrict__ bq, const float* __restrict__ bk,
    const float* __restrict__ bv, float* __restrict__ bqkv,
    const float* __restrict__ Wq, const float* __restrict__ Wk,
    const float* __restrict__ Wv, const float* __restrict__ Wo,
    const float* __restrict__ W1, const float* __restrict__ W2,
    bf16* __restrict__ Wqkvt, bf16* __restrict__ Wot,
    bf16* __restrict__ W1t, bf16* __restrict__ W2t,
    const float* __restrict__ biasP, f16* __restrict__ biasH,
    const unsigned* __restrict__ mqe) {
  __shared__ float t[32][33];
  const int tid = threadIdx.x;
  int id = blockIdx.x;
  if (id < 4096) {
    const int i = id * 256 + tid;  // float4 index
    float4 v = ((const float4*)src)[i];
    uint2 w;
    w.x = pk_bf16(v.x, v.y);
    w.y = pk_bf16(v.z, v.w);
    ((uint2*)xb)[i] = w;
    return;
  }
  id -= 4096;
  if (id < 12) {
    const int i = id * 256 + tid;
    if (i < L_ * 768) {
      const int l = i / 768, n = i - l * 768;
      float v = (n < 256) ? bq[l * 256 + n]
              : (n < 512) ? bk[l * 256 + n - 256]
                          : bv[l * 256 + n - 512];
      bqkv[i] = v;
    }
    return;
  }
  id -= 12;
  if (id < 1024) {
    const int w = id >> 8, tt = id & 255;
    const int l = tt >> 6, tile = tt & 63;
    const int n0 = (tile & 7) * 32, k0 = (tile >> 3) * 32;
    const float* W = (w == 0) ? Wq : (w == 1) ? Wk : (w == 2) ? Wv : Wo;
    bf16* Wt = (w == 3) ? Wot : (Wqkvt + w * 65536);
    const size_t outL = (w == 3) ? 65536 : 196608;
    convT_tile(W, Wt, 256, 256, 65536, outL, l, k0, n0, tid, t);
    return;
  }
  id -= 1024;
  if (id < 1024) {
    const int l = id >> 8, tile = id & 255;
    const int n0 = (tile & 31) * 32, k0 = (tile >> 5) * 32;
    convT_tile(W1, W1t, 256, 1024, 262144, 262144, l, k0, n0, tid, t);
    return;
  }
  id -= 1024;
  if (id < 1024) {
    const int l = id >> 8, tile = id & 255;
    const int n0 = (tile & 7) * 32, k0 = (tile >> 3) * 32;
    convT_tile(W2, W2t, 1024, 256, 262144, 262144, l, k0, n0, tid, t);
    return;
  }
  id -= 1024;
  {
    const int i = id * 256 + tid;  // 65536 float4
    const float4 v = ((const float4*)biasP)[i];
    const float m = decf(mqe[i & 511]);
    v4h o;
    o[0] = (f16)(v.x - m); o[1] = (f16)(v.y - m);
    o[2] = (f16)(v.z - m); o[3] = (f16)(v.w - m);
    *(v4h*)&biasH[(size_t)i * 4] = o;
  }
}

// ---------------- bf16 MFMA GEMM, 2-phase pipelined, XCD-swizzled ----------------
// OUTMODE: 0 = fp32 row-major, 1 = bf16 row-major, 2 = bf16 head-major QKV (N=768)
template <int BM, int BN, int WPC, int RELU, int OUTMODE, int RESID>
__global__ __launch_bounds__(256, WPC) void gemm_bf16k(
    const bf16* __restrict__ A, const bf16* __restrict__ Bt,
    const float* __restrict__ bias, const bf16* __restrict__ resid,
    void* __restrict__ Cout, int M, int N, int K, int nbx) {
  constexpr int MR = BM / 32, NR = BN / 32;
  constexpr int NSLAB = (BM + BN) / 16;
  constexpr int LPW = NSLAB / 4;
  constexpr int BUFE = (BM + BN) * 32;
  __shared__ __align__(16) bf16 lds[3 * BUFE];
  const int tid  = threadIdx.x;
  const int wave = tid >> 6, lane = tid & 63;
  const int l15 = lane & 15, l4 = lane >> 4;
  const int qq = gridDim.x >> 3;
  const int wg = (blockIdx.x & 7) * qq + (blockIdx.x >> 3);
  const int bx = wg % nbx, by = wg / nbx;
  const int bm = by * BM, bn = bx * BN;
  const int wr = (wave >> 1) * (BM / 2), wc = (wave & 1) * (BN / 2);
  const int lrow = lane >> 2;
  const int lk   = (lane & 3) * 8;

  v4f acc[MR][NR];
#pragma unroll
  for (int m = 0; m < MR; ++m)
#pragma unroll
    for (int n = 0; n < NR; ++n) acc[m][n] = (v4f){0.f, 0.f, 0.f, 0.f};

  auto STAGE = [&](int buf, int k0) {
    bf16* dst = &lds[buf * BUFE];
#pragma unroll
    for (int s = wave; s < NSLAB; s += 4) {
      if (s < BM / 16)
        gload16(A + (size_t)(bm + s * 16 + lrow) * K + k0 + lk, dst + s * 512);
      else
        gload16(Bt + (size_t)(bn + (s - BM / 16) * 16 + lrow) * K + k0 + lk, dst + s * 512);
    }
  };

  const int nk = K >> 5;
  STAGE(0, 0);
  STAGE(1, 32);
  waitvm<LPW>();
  __builtin_amdgcn_s_barrier();
  __builtin_amdgcn_sched_barrier(0);

  int cur = 0;
  for (int t = 0; t < nk; ++t) {
    const bool pf = (t + 2 < nk);
    if (pf) STAGE(cur == 0 ? 2 : cur - 1, (t + 2) * 32);
    const bf16* buf = &lds[cur * BUFE];
    v8bf af[MR], bfr[NR];
#pragma unroll
    for (int m = 0; m < MR; ++m)
      af[m] = *(const v8bf*)&buf[(wr + m * 16 + l15) * 32 + l4 * 8];
#pragma unroll
    for (int n = 0; n < NR; ++n)
      bfr[n] = *(const v8bf*)&buf[BM * 32 + (wc + n * 16 + l15) * 32 + l4 * 8];
    __builtin_amdgcn_s_setprio(1);
#pragma unroll
    for (int m = 0; m < MR; ++m)
#pragma unroll
      for (int n = 0; n < NR; ++n)
        acc[m][n] = __builtin_amdgcn_mfma_f32_16x16x32_bf16(af[m], bfr[n], acc[m][n], 0, 0, 0);
    __builtin_amdgcn_s_setprio(0);
    if (pf) waitvm<LPW>();
    else    waitvm<0>();
    __builtin_amdgcn_s_barrier();
    __builtin_amdgcn_sched_barrier(0);
    cur = (cur == 2) ? 0 : cur + 1;
  }

#pragma unroll
  for (int m = 0; m < MR; ++m) {
    const int row0 = bm + wr + m * 16 + l4 * 4;
#pragma unroll
    for (int n = 0; n < NR; ++n) {
      const int col = bn + wc + n * 16 + l15;
      const float bc = bias[col];
      if constexpr (OUTMODE == 2) {
        // head-major QKV: sec (q/k/v), head, d
        const int sec = col >> 8, hh = (col >> 5) & 7, d = col & 31;
        const int bb = row0 >> 9, nr0 = row0 & 511;
        bf16* dst = (bf16*)Cout + (size_t)sec * QHSZ +
                    (((size_t)bb * 8 + hh) * 512 + nr0) * 32 + d;
#pragma unroll
        for (int i = 0; i < 4; ++i)
          dst[i * 32] = (bf16)(acc[m][n][i] + bc);
      } else {
#pragma unroll
        for (int i = 0; i < 4; ++i) {
          const size_t idx = (size_t)(row0 + i) * N + col;
          float v = acc[m][n][i] + bc;
          if (RESID) v += (float)resid[idx];
          if (RELU) v = fmaxf(v, 0.f);
          if (OUTMODE == 1) ((bf16*)Cout)[idx] = (bf16)v;
          else              ((float*)Cout)[idx] = v;
        }
      }
    }
  }
}

// ---------------- fused flash attention, head-major QKV, fixed normalizer, fp16 bias ----------------
// 512 threads / 8 waves; 2 blocks per (b,h) (256 q-rows each); grid 512 = 2 blocks/CU
#define VTS 520
__global__ __launch_bounds__(512, 2) void attn_k(
    const bf16* __restrict__ qkvh, const f16* __restrict__ biasH,
    bf16* __restrict__ outp) {
  __shared__ u16 Vt[32 * VTS];   // V^T: [d][kc]
  const int tid = threadIdx.x;
  const int wave = tid >> 6, lane = tid & 63;
  const int l31 = lane & 31, hi = lane >> 5;
  const int fid = blockIdx.x;            // [0,512)
  const int xcd = fid & 7, idx = fid >> 3;   // idx [0,64)
  const int b = (xcd << 2) | (idx >> 4);
  const int h = (idx >> 1) & 7;
  const int qhalf = idx & 1;
  const u16* Qh = (const u16*)qkvh + (((size_t)b * 8 + h) * 512) * 32;
  const u16* Kh = Qh + QHSZ;
  const u16* Vh = Qh + 2 * QHSZ;
  const int qb = qhalf * 256 + wave * 32;

  // ---- stage V^T (once per block): thread t packs row t (contiguous stream) ----
  {
    const u16* p0 = Vh + (size_t)tid * 32;
#pragma unroll
    for (int d0 = 0; d0 < 32; d0 += 8) {
      v8us a = *(const v8us*)(p0 + d0);
#pragma unroll
      for (int j = 0; j < 8; ++j)
        Vt[(d0 + j) * VTS + tid] = a[j];
    }
  }
  __syncthreads();

  // ---- Q fragments (B operand), held all chunks ----
  const u16* qrow = Qh + (size_t)(qb + l31) * 32;
  const v8bf qf0 = *(const v8bf*)(qrow + hi * 8);
  const v8bf qf1 = *(const v8bf*)(qrow + 16 + hi * 8);
  const f16* bpl = biasH + ((size_t)(hi * 512 + qb + l31)) * 4;

  const float SC2 = 0.17677669529663688f * 1.4426950408889634f;
  float lsum = 0.f;
  v16f accO = {0.f,0.f,0.f,0.f,0.f,0.f,0.f,0.f,0.f,0.f,0.f,0.f,0.f,0.f,0.f,0.f};

  v8bf ka0 = *(const v8bf*)(Kh + (size_t)l31 * 32 + hi * 8);
  v8bf ka1 = *(const v8bf*)(Kh + (size_t)l31 * 32 + 16 + hi * 8);
  v4h bb[4];
#pragma unroll
  for (int g = 0; g < 4; ++g) bb[g] = *(const v4h*)(bpl + (size_t)(g * 2) * 2048);

  v16f stC = {0.f,0.f,0.f,0.f,0.f,0.f,0.f,0.f,0.f,0.f,0.f,0.f,0.f,0.f,0.f,0.f};
  stC = __builtin_amdgcn_mfma_f32_32x32x16_bf16(ka0, qf0, stC, 0, 0, 0);
  stC = __builtin_amdgcn_mfma_f32_32x32x16_bf16(ka1, qf1, stC, 0, 0, 0);
  {
    const u16* kn = Kh + (size_t)(32 + l31) * 32;
    ka0 = *(const v8bf*)(kn + hi * 8);
    ka1 = *(const v8bf*)(kn + 16 + hi * 8);
  }

  for (int kb = 0; kb < 16; ++kb) {
    const int kbase = kb * 32;
    // QK^T(kb+1) early: matrix pipe runs under softmax VALU of chunk kb
    v16f stN = {0.f,0.f,0.f,0.f,0.f,0.f,0.f,0.f,0.f,0.f,0.f,0.f,0.f,0.f,0.f,0.f};
    __builtin_amdgcn_s_setprio(1);
    stN = __builtin_amdgcn_mfma_f32_32x32x16_bf16(ka0, qf0, stN, 0, 0, 0);
    stN = __builtin_amdgcn_mfma_f32_32x32x16_bf16(ka1, qf1, stN, 0, 0, 0);
    __builtin_amdgcn_s_setprio(0);

    // prefetch K(kb+2) and bias(kb+1)  (unconditional; reads spill into padded region = valid)
    const u16* kn = Kh + (size_t)(kbase + 64 + l31) * 32;
    const v8bf kn0 = *(const v8bf*)(kn + hi * 8);
    const v8bf kn1 = *(const v8bf*)(kn + 16 + hi * 8);
    v4h bn[4];
#pragma unroll
    for (int g = 0; g < 4; ++g)
      bn[g] = *(const v4h*)(bpl + (size_t)((kb + 1) * 8 + g * 2) * 2048);

    float p[16];
#pragma unroll
    for (int r = 0; r < 16; ++r)
      p[r] = EXP2(fmaf(stC[r], SC2, (float)bb[r >> 2][r & 3]));

    float s8[8], s4[4];
#pragma unroll
    for (int r = 0; r < 8; ++r) s8[r] = p[r] + p[r + 8];
#pragma unroll
    for (int r = 0; r < 4; ++r) s4[r] = s8[r] + s8[r + 4];
    lsum += (s4[0] + s4[2]) + (s4[1] + s4[3]);

    unsigned u[8];
#pragma unroll
    for (int t = 0; t < 8; ++t) u[t] = pk_bf16(p[2 * t], p[2 * t + 1]);
    PLSWAP(u[0], u[2]);
    PLSWAP(u[1], u[3]);
    PLSWAP(u[4], u[6]);
    PLSWAP(u[5], u[7]);
    union { v4u u; v8bf h; } cv0, cv1;
    cv0.u = (v4u){u[0], u[1], u[2], u[3]};
    cv1.u = (v4u){u[4], u[5], u[6], u[7]};

    const v8bf va0 = *(const v8bf*)&Vt[l31 * VTS + kbase + hi * 8];
    const v8bf va1 = *(const v8bf*)&Vt[l31 * VTS + kbase + 16 + hi * 8];
    __builtin_amdgcn_s_setprio(1);
    accO = __builtin_amdgcn_mfma_f32_32x32x16_bf16(va0, cv0.h, accO, 0, 0, 0);
    accO = __builtin_amdgcn_mfma_f32_32x32x16_bf16(va1, cv1.h, accO, 0, 0, 0);
    __builtin_amdgcn_s_setprio(0);

    stC = stN;
    ka0 = kn0; ka1 = kn1;
#pragma unroll
    for (int g = 0; g < 4; ++g) bb[g] = bn[g];
  }

  lsum += __shfl_xor(lsum, 32);

  const float inv = 1.0f / lsum;
  u16* orow = (u16*)outp + (size_t)(b * N_ + qb + l31) * D_ + h * 32 + 4 * hi;
#pragma unroll
  for (int g = 0; g < 4; ++g) {
    uint2 w;
    w.x = pk_bf16(accO[4 * g] * inv, accO[4 * g + 1] * inv);
    w.y = pk_bf16(accO[4 * g + 2] * inv, accO[4 * g + 3] * inv);
    *(uint2*)(orow + 8 * g) = w;
  }
}

// ---------------- LayerNorm: fp32 in; 8 rows/block (2 rows/wave, interleaved) ----------------
// MODE 0 -> xb bf16 out, MODE 1 -> fp32 out
template <int MODE>
__global__ __launch_bounds__(256) void ln_kernel(
    const float* __restrict__ xin,
    const float* __restrict__ g, const float* __restrict__ b,
    float* __restrict__ xout_f32, bf16* __restrict__ xbout) {
  const int wv = threadIdx.x >> 6, ln = threadIdx.x & 63;
  const size_t row0 = (size_t)blockIdx.x * 8 + wv * 2;
  const size_t oA = row0 * D_ + ln * 4;
  const size_t oB = oA + D_;
  const float4 vA = *(const float4*)&xin[oA];
  const float4 vB = *(const float4*)&xin[oB];
  float sA  = (vA.x + vA.y) + (vA.z + vA.w);
  float ssA = (vA.x * vA.x + vA.y * vA.y) + (vA.z * vA.z + vA.w * vA.w);
  float sB  = (vB.x + vB.y) + (vB.z + vB.w);
  float ssB = (vB.x * vB.x + vB.y * vB.y) + (vB.z * vB.z + vB.w * vB.w);
#pragma unroll
  for (int off = 1; off < 64; off <<= 1) {
    sA  += __shfl_xor(sA, off);
    ssA += __shfl_xor(ssA, off);
    sB  += __shfl_xor(sB, off);
    ssB += __shfl_xor(ssB, off);
  }
  const float muA = sA * (1.f / D_);
  const float muB = sB * (1.f / D_);
  const float rsA = rsqrtf(ssA * (1.f / D_) - muA * muA + 1e-5f);
  const float rsB = rsqrtf(ssB * (1.f / D_) - muB * muB + 1e-5f);
  const float4 gg = *(const float4*)&g[ln * 4];
  const float4 bb = *(const float4*)&b[ln * 4];
  float4 oAv, oBv;
  oAv.x = (vA.x - muA) * rsA * gg.x + bb.x;
  oAv.y = (vA.y - muA) * rsA * gg.y + bb.y;
  oAv.z = (vA.z - muA) * rsA * gg.z + bb.z;
  oAv.w = (vA.w - muA) * rsA * gg.w + bb.w;
  oBv.x = (vB.x - muB) * rsB * gg.x + bb.x;
  oBv.y = (vB.y - muB) * rsB * gg.y + bb.y;
  oBv.z = (vB.z - muB) * rsB * gg.z + bb.z;
  oBv.w = (vB.w - muB) * rsB * gg.w + bb.w;
  if constexpr (MODE == 1) {
    *(float4*)&xout_f32[oA] = oAv;
    *(float4*)&xout_f32[oB] = oBv;
  } else {
    uint2 wA, wB;
    wA.x = pk_bf16(oAv.x, oAv.y);
    wA.y = pk_bf16(oAv.z, oAv.w);
    wB.x = pk_bf16(oBv.x, oBv.y);
    wB.y = pk_bf16(oBv.z, oBv.w);
    *(uint2*)&xbout[oA] = wA;
    *(uint2*)&xbout[oB] = wB;
  }
}

extern "C" void kernel_launch(void* const* d_in, const int* in_sizes, int n_in,
                              void* d_out, int out_size, void* d_ws, size_t ws_size,
                              hipStream_t stream) {
  const float* src = (const float*)d_in[0];
  const float* e1  = (const float*)d_in[1];
  const float* e2  = (const float*)d_in[2];
  const float* Wq  = (const float*)d_in[3];
  const float* bq  = (const float*)d_in[4];
  const float* Wk  = (const float*)d_in[5];
  const float* bk  = (const float*)d_in[6];
  const float* Wv  = (const float*)d_in[7];
  const float* bv  = (const float*)d_in[8];
  const float* Wo  = (const float*)d_in[9];
  const float* bo  = (const float*)d_in[10];
  const float* W1  = (const float*)d_in[11];
  const float* b1  = (const float*)d_in[12];
  const float* W2  = (const float*)d_in[13];
  const float* b2  = (const float*)d_in[14];
  const float* g1  = (const float*)d_in[15];
  const float* be1 = (const float*)d_in[16];
  const float* g2  = (const float*)d_in[17];
  const float* be2 = (const float*)d_in[18];

  char* ws = (char*)d_ws;
  size_t off = 0;
  auto alloc = [&](size_t bytes) {
    void* p = ws + off;
    off += (bytes + 255) & ~(size_t)255;
    return p;
  };
  float*    biasP  = (float*)alloc((size_t)1024 * 1024 + 4096);  // fp32, pre-subtraction
  f16*      biasH  = (f16*)  alloc((size_t)2 * 1024 * 1024);     // fp16, 0.52MB used + prefetch pad
  unsigned* mqe    = (unsigned*)alloc((size_t)N_ * 4);
  bf16*     xb     = (bf16*) alloc((size_t)ROWS * D_ * 2);
  bf16*     attn_o = (bf16*) alloc((size_t)ROWS * D_ * 2);
  float*    tmpf   = (float*)alloc((size_t)ROWS * D_ * 4);
  bf16*     qkvh   = (bf16*) alloc((size_t)ROWS * 1024 * 2 + 65536);  // shared: head-major qkv / ffn h1
  bf16*     h1     = qkvh;
  bf16*     Wqkvt  = (bf16*) alloc((size_t)L_ * 768 * 256 * 2);
  bf16*     Wot    = (bf16*) alloc((size_t)L_ * 256 * 256 * 2);
  bf16*     W1t    = (bf16*) alloc((size_t)L_ * 1024 * 256 * 2);
  bf16*     W2t    = (bf16*) alloc((size_t)L_ * 256 * 1024 * 2);
  float*    bqkv   = (float*)alloc((size_t)L_ * 768 * 4);

  hipMemsetAsync(mqe, 0, (size_t)N_ * 4, stream);
  // biasT[k][q] = e2[k] . e1[q]  -> eK = e2, eQ = e1
  bias_gemm<<<dim3(16, 16), dim3(16, 16), 0, stream>>>(e2, e1, biasP, mqe);
  setup_all<<<7436, 256, 0, stream>>>(
      src, xb, bq, bk, bv, bqkv,
      Wq, Wk, Wv, Wo, W1, W2, Wqkvt, Wot, W1t, W2t, biasP, biasH, mqe);

  for (int l = 0; l < L_; ++l) {
    // QKV: M=16384, N=768, K=256; 128x128, head-major output
    gemm_bf16k<128, 128, 3, 0, 2, 0><<<768, 256, 0, stream>>>(
        xb, Wqkvt + (size_t)l * 196608, bqkv + l * 768, nullptr, qkvh,
        ROWS, 768, 256, 6);
    attn_k<<<512, 512, 0, stream>>>(qkvh, biasH, attn_o);
    // Wo + residual(xb): 64x128, fp32 tmpf out
    gemm_bf16k<64, 128, 4, 0, 0, 1><<<512, 256, 0, stream>>>(
        attn_o, Wot + (size_t)l * 65536, bo + l * 256, xb, tmpf,
        ROWS, 256, 256, 2);
    ln_kernel<0><<<ROWS / 8, 256, 0, stream>>>(tmpf, g1 + l * 256, be1 + l * 256, nullptr, xb);
    // W1 + ReLU: 128x256 (2/CU, single residency round), bf16 out
    gemm_bf16k<128, 256, 2, 1, 1, 0><<<512, 256, 0, stream>>>(
        xb, W1t + (size_t)l * 262144, b1 + l * 1024, nullptr, h1,
        ROWS, 1024, 256, 4);
    // W2 + residual(xb): 64x128, fp32 tmpf out
    gemm_bf16k<64, 128, 4, 0, 0, 1><<<512, 256, 0, stream>>>(
        h1, W2t + (size_t)l * 262144, b2 + l * 256, xb, tmpf,
        ROWS, 256, 1024, 2);
    if (l == L_ - 1)
      ln_kernel<1><<<ROWS / 8, 256, 0, stream>>>(tmpf, g2 + l * 256, be2 + l * 256, (float*)d_out, nullptr);
    else
      ln_kernel<0><<<ROWS / 8, 256, 0, stream>>>(tmpf, g2 + l * 256, be2 + l * 256, nullptr, xb);
  }
}

// Round 19
// 391.649 us; speedup vs baseline: 1.5323x; 1.0934x over previous
//
#include <hip/hip_runtime.h>

typedef __bf16 bf16;
typedef __bf16 v4bf __attribute__((ext_vector_type(4)));
typedef __bf16 v8bf __attribute__((ext_vector_type(8)));
typedef float  v4f  __attribute__((ext_vector_type(4)));
typedef float  v16f __attribute__((ext_vector_type(16)));
typedef unsigned short u16;
typedef u16 v8us __attribute__((ext_vector_type(8)));
typedef unsigned int v4u __attribute__((ext_vector_type(4)));
typedef _Float16 f16;
typedef f16 v4h __attribute__((ext_vector_type(4)));

#define L_ 4
#define B_ 32
#define N_ 512
#define D_ 256
#define H_ 8
#define F_ 1024
#define ROWS (B_*N_)               // 16384
#define QHSZ ((size_t)B_*H_*N_*32) // elems per Q/K/V head-major section

__device__ __forceinline__ void gload16(const void* g, void* l) {
  __builtin_amdgcn_global_load_lds((__attribute__((address_space(1))) void*)g,
                                   (__attribute__((address_space(3))) void*)l,
                                   16, 0, 0);
}

__device__ __forceinline__ unsigned pk_bf16(float a, float b) {
  unsigned r;
  asm("v_cvt_pk_bf16_f32 %0, %1, %2" : "=v"(r) : "v"(a), "v"(b));
  return r;
}

// swap: a.hi <-> b.lo
#define PLSWAP(a, b) asm volatile("v_permlane32_swap_b32 %0, %1" : "+v"(a), "+v"(b))

#define EXP2(x) __builtin_amdgcn_exp2f(x)

// monotone float<->uint encoding for atomicMax
__device__ __forceinline__ unsigned encf(float f) {
  unsigned u = __float_as_uint(f);
  return (u & 0x80000000u) ? ~u : (u | 0x80000000u);
}
__device__ __forceinline__ float decf(unsigned e) {
  unsigned b = (e & 0x80000000u) ? (e & 0x7fffffffu) : ~e;
  return __uint_as_float(b);
}

template <int N> __device__ __forceinline__ void waitvm() {
  if constexpr (N == 0) asm volatile("s_waitcnt vmcnt(0)" ::: "memory");
  else if constexpr (N == 2) asm volatile("s_waitcnt vmcnt(2)" ::: "memory");
  else if constexpr (N == 3) asm volatile("s_waitcnt vmcnt(3)" ::: "memory");
  else if constexpr (N == 4) asm volatile("s_waitcnt vmcnt(4)" ::: "memory");
  else if constexpr (N == 5) asm volatile("s_waitcnt vmcnt(5)" ::: "memory");
  else if constexpr (N == 6) asm volatile("s_waitcnt vmcnt(6)" ::: "memory");
}

// ---------------- biasP (permuted, MFMA C-layout) = (eK @ eQ^T) * log2e; also mq = colmax ----------------
// biasT[k][q] = eK[k] . eQ[q]  (called with eK = e2, eQ = e1)
// 32x32 tile, 2x2 per thread; grid 16x16 = 256 blocks (full machine)
__global__ __launch_bounds__(256) void bias_gemm(
    const float* __restrict__ eK, const float* __restrict__ eQ,
    float* __restrict__ biasP, unsigned* __restrict__ mqe) {
  __shared__ float As[32][17];   // eK rows (k)
  __shared__ float Bs[32][17];   // eQ rows (q)
  __shared__ float pm[16][32];
  const int tx = threadIdx.x, ty = threadIdx.y;     // 16x16
  const int t = ty * 16 + tx;
  const int lrow = t >> 3, lkq = (t & 7) * 2;
  const int r0 = blockIdx.y * 32, c0 = blockIdx.x * 32;
  float acc[2][2] = {{0.f, 0.f}, {0.f, 0.f}};
  for (int k0 = 0; k0 < D_; k0 += 16) {
    const float2 a2 = *(const float2*)&eK[(size_t)(r0 + lrow) * D_ + k0 + lkq];
    const float2 b2 = *(const float2*)&eQ[(size_t)(c0 + lrow) * D_ + k0 + lkq];
    As[lrow][lkq] = a2.x; As[lrow][lkq + 1] = a2.y;
    Bs[lrow][lkq] = b2.x; Bs[lrow][lkq + 1] = b2.y;
    __syncthreads();
#pragma unroll
    for (int k = 0; k < 16; ++k) {
      const float a0 = As[ty * 2][k], a1 = As[ty * 2 + 1][k];
      const float b0 = Bs[tx * 2][k], b1 = Bs[tx * 2 + 1][k];
      acc[0][0] += a0 * b0; acc[0][1] += a0 * b1;
      acc[1][0] += a1 * b0; acc[1][1] += a1 * b1;
    }
    __syncthreads();
  }
#pragma unroll
  for (int i = 0; i < 2; ++i)
#pragma unroll
    for (int j = 0; j < 2; ++j) acc[i][j] *= 1.4426950408889634f;
  // permuted write: row gr = k-index, col q
#pragma unroll
  for (int i = 0; i < 2; ++i) {
    const int gr = r0 + ty * 2 + i;
    const int kb = gr >> 5, r5 = gr & 31;
    const int blk = kb * 8 + (r5 >> 3) * 2 + ((r5 >> 2) & 1);
#pragma unroll
    for (int j = 0; j < 2; ++j) {
      const int q = c0 + tx * 2 + j;
      biasP[(size_t)(blk * 512 + q) * 4 + (r5 & 3)] = acc[i][j];
    }
  }
  // block-local column max -> atomics
  pm[ty][tx * 2]     = fmaxf(acc[0][0], acc[1][0]);
  pm[ty][tx * 2 + 1] = fmaxf(acc[0][1], acc[1][1]);
  __syncthreads();
  if (ty == 0) {
#pragma unroll
    for (int j = 0; j < 2; ++j) {
      float m = pm[0][tx * 2 + j];
#pragma unroll
      for (int y = 1; y < 16; ++y) m = fmaxf(m, pm[y][tx * 2 + j]);
      atomicMax(&mqe[c0 + tx * 2 + j], encf(m));
    }
  }
}

// ---------------- unified setup: init_x + pack_bqkv + all weight transposes + subm->fp16 ----------------
__device__ __forceinline__ void convT_tile(
    const float* __restrict__ W, bf16* __restrict__ Wt,
    int K, int N, size_t inL, size_t outL, int l, int k0, int n0, int tid,
    float (*t)[33]) {
  const int r = tid >> 5, c = tid & 31;
#pragma unroll
  for (int i = 0; i < 4; ++i)
    t[r + 8 * i][c] = W[l * inL + (size_t)(k0 + r + 8 * i) * N + n0 + c];
  __syncthreads();
#pragma unroll
  for (int i = 0; i < 4; ++i)
    Wt[l * outL + (size_t)(n0 + r + 8 * i) * K + k0 + c] = (bf16)t[c][r + 8 * i];
}

// blocks: [0,4096) init_x | [4096,4108) pack_bqkv | [4108,5132) Wq/Wk/Wv/Wo |
//         [5132,6156) W1 | [6156,7180) W2 | [7180,7436) subm: biasH = f16(biasP - mq)
__global__ __launch_bounds__(256) void setup_all(
    const float* __restrict__ src, bf16* __restrict__ xb,
    const float* __restrict__ bq, const float* __restrict__ bk,
    const float* __restrict__ bv, float* __restrict__ bqkv,
    const float* __restrict__ Wq, const float* __restrict__ Wk,
    const float* __restrict__ Wv, const float* __restrict__ Wo,
    const float* __restrict__ W1, const float* __restrict__ W2,
    bf16* __restrict__ Wqkvt, bf16* __restrict__ Wot,
    bf16* __restrict__ W1t, bf16* __restrict__ W2t,
    const float* __restrict__ biasP, f16* __restrict__ biasH,
    const unsigned* __restrict__ mqe) {
  __shared__ float t[32][33];
  const int tid = threadIdx.x;
  int id = blockIdx.x;
  if (id < 4096) {
    const int i = id * 256 + tid;  // float4 index
    float4 v = ((const float4*)src)[i];
    uint2 w;
    w.x = pk_bf16(v.x, v.y);
    w.y = pk_bf16(v.z, v.w);
    ((uint2*)xb)[i] = w;
    return;
  }
  id -= 4096;
  if (id < 12) {
    const int i = id * 256 + tid;
    if (i < L_ * 768) {
      const int l = i / 768, n = i - l * 768;
      float v = (n < 256) ? bq[l * 256 + n]
              : (n < 512) ? bk[l * 256 + n - 256]
                          : bv[l * 256 + n - 512];
      bqkv[i] = v;
    }
    return;
  }
  id -= 12;
  if (id < 1024) {
    const int w = id >> 8, tt = id & 255;
    const int l = tt >> 6, tile = tt & 63;
    const int n0 = (tile & 7) * 32, k0 = (tile >> 3) * 32;
    const float* W = (w == 0) ? Wq : (w == 1) ? Wk : (w == 2) ? Wv : Wo;
    bf16* Wt = (w == 3) ? Wot : (Wqkvt + w * 65536);
    const size_t outL = (w == 3) ? 65536 : 196608;
    convT_tile(W, Wt, 256, 256, 65536, outL, l, k0, n0, tid, t);
    return;
  }
  id -= 1024;
  if (id < 1024) {
    const int l = id >> 8, tile = id & 255;
    const int n0 = (tile & 31) * 32, k0 = (tile >> 5) * 32;
    convT_tile(W1, W1t, 256, 1024, 262144, 262144, l, k0, n0, tid, t);
    return;
  }
  id -= 1024;
  if (id < 1024) {
    const int l = id >> 8, tile = id & 255;
    const int n0 = (tile & 7) * 32, k0 = (tile >> 3) * 32;
    convT_tile(W2, W2t, 1024, 256, 262144, 262144, l, k0, n0, tid, t);
    return;
  }
  id -= 1024;
  {
    const int i = id * 256 + tid;  // 65536 float4
    const float4 v = ((const float4*)biasP)[i];
    const float m = decf(mqe[i & 511]);
    v4h o;
    o[0] = (f16)(v.x - m); o[1] = (f16)(v.y - m);
    o[2] = (f16)(v.z - m); o[3] = (f16)(v.w - m);
    *(v4h*)&biasH[(size_t)i * 4] = o;
  }
}

// ---------------- bf16 MFMA GEMM, 2-phase pipelined, XCD-swizzled ----------------
// OUTMODE: 0 = fp32 row-major, 1 = bf16 row-major, 2 = bf16 head-major QKV (N=768)
template <int BM, int BN, int WPC, int RELU, int OUTMODE, int RESID>
__global__ __launch_bounds__(256, WPC) void gemm_bf16k(
    const bf16* __restrict__ A, const bf16* __restrict__ Bt,
    const float* __restrict__ bias, const bf16* __restrict__ resid,
    void* __restrict__ Cout, int M, int N, int K, int nbx) {
  constexpr int MR = BM / 32, NR = BN / 32;
  constexpr int NSLAB = (BM + BN) / 16;
  constexpr int LPW = NSLAB / 4;
  constexpr int BUFE = (BM + BN) * 32;
  __shared__ __align__(16) bf16 lds[3 * BUFE];
  const int tid  = threadIdx.x;
  const int wave = tid >> 6, lane = tid & 63;
  const int l15 = lane & 15, l4 = lane >> 4;
  const int qq = gridDim.x >> 3;
  const int wg = (blockIdx.x & 7) * qq + (blockIdx.x >> 3);
  const int bx = wg % nbx, by = wg / nbx;
  const int bm = by * BM, bn = bx * BN;
  const int wr = (wave >> 1) * (BM / 2), wc = (wave & 1) * (BN / 2);
  const int lrow = lane >> 2;
  const int lk   = (lane & 3) * 8;

  v4f acc[MR][NR];
#pragma unroll
  for (int m = 0; m < MR; ++m)
#pragma unroll
    for (int n = 0; n < NR; ++n) acc[m][n] = (v4f){0.f, 0.f, 0.f, 0.f};

  auto STAGE = [&](int buf, int k0) {
    bf16* dst = &lds[buf * BUFE];
#pragma unroll
    for (int s = wave; s < NSLAB; s += 4) {
      if (s < BM / 16)
        gload16(A + (size_t)(bm + s * 16 + lrow) * K + k0 + lk, dst + s * 512);
      else
        gload16(Bt + (size_t)(bn + (s - BM / 16) * 16 + lrow) * K + k0 + lk, dst + s * 512);
    }
  };

  const int nk = K >> 5;
  STAGE(0, 0);
  STAGE(1, 32);
  waitvm<LPW>();
  __builtin_amdgcn_s_barrier();
  __builtin_amdgcn_sched_barrier(0);

  int cur = 0;
  for (int t = 0; t < nk; ++t) {
    const bool pf = (t + 2 < nk);
    if (pf) STAGE(cur == 0 ? 2 : cur - 1, (t + 2) * 32);
    const bf16* buf = &lds[cur * BUFE];
    v8bf af[MR], bfr[NR];
#pragma unroll
    for (int m = 0; m < MR; ++m)
      af[m] = *(const v8bf*)&buf[(wr + m * 16 + l15) * 32 + l4 * 8];
#pragma unroll
    for (int n = 0; n < NR; ++n)
      bfr[n] = *(const v8bf*)&buf[BM * 32 + (wc + n * 16 + l15) * 32 + l4 * 8];
    __builtin_amdgcn_s_setprio(1);
#pragma unroll
    for (int m = 0; m < MR; ++m)
#pragma unroll
      for (int n = 0; n < NR; ++n)
        acc[m][n] = __builtin_amdgcn_mfma_f32_16x16x32_bf16(af[m], bfr[n], acc[m][n], 0, 0, 0);
    __builtin_amdgcn_s_setprio(0);
    if (pf) waitvm<LPW>();
    else    waitvm<0>();
    __builtin_amdgcn_s_barrier();
    __builtin_amdgcn_sched_barrier(0);
    cur = (cur == 2) ? 0 : cur + 1;
  }

#pragma unroll
  for (int m = 0; m < MR; ++m) {
    const int row0 = bm + wr + m * 16 + l4 * 4;
#pragma unroll
    for (int n = 0; n < NR; ++n) {
      const int col = bn + wc + n * 16 + l15;
      const float bc = bias[col];
      if constexpr (OUTMODE == 2) {
        // head-major QKV: sec (q/k/v), head, d
        const int sec = col >> 8, hh = (col >> 5) & 7, d = col & 31;
        const int bb = row0 >> 9, nr0 = row0 & 511;
        bf16* dst = (bf16*)Cout + (size_t)sec * QHSZ +
                    (((size_t)bb * 8 + hh) * 512 + nr0) * 32 + d;
#pragma unroll
        for (int i = 0; i < 4; ++i)
          dst[i * 32] = (bf16)(acc[m][n][i] + bc);
      } else {
#pragma unroll
        for (int i = 0; i < 4; ++i) {
          const size_t idx = (size_t)(row0 + i) * N + col;
          float v = acc[m][n][i] + bc;
          if (RESID) v += (float)resid[idx];
          if (RELU) v = fmaxf(v, 0.f);
          if (OUTMODE == 1) ((bf16*)Cout)[idx] = (bf16)v;
          else              ((float*)Cout)[idx] = v;
        }
      }
    }
  }
}

// ---------------- fused flash attention, head-major QKV, fixed normalizer, fp16 bias ----------------
// 512 threads / 8 waves; 2 blocks per (b,h) (256 q-rows each); grid 512 = 2 blocks/CU
#define VTS 520
__global__ __launch_bounds__(512, 2) void attn_k(
    const bf16* __restrict__ qkvh, const f16* __restrict__ biasH,
    bf16* __restrict__ outp) {
  __shared__ u16 Vt[32 * VTS];   // V^T: [d][kc]
  const int tid = threadIdx.x;
  const int wave = tid >> 6, lane = tid & 63;
  const int l31 = lane & 31, hi = lane >> 5;
  const int fid = blockIdx.x;            // [0,512)
  const int xcd = fid & 7, idx = fid >> 3;   // idx [0,64)
  const int b = (xcd << 2) | (idx >> 4);
  const int h = (idx >> 1) & 7;
  const int qhalf = idx & 1;
  const u16* Qh = (const u16*)qkvh + (((size_t)b * 8 + h) * 512) * 32;
  const u16* Kh = Qh + QHSZ;
  const u16* Vh = Qh + 2 * QHSZ;
  const int qb = qhalf * 256 + wave * 32;

  // ---- stage V^T (once per block): thread t packs row t (contiguous stream) ----
  {
    const u16* p0 = Vh + (size_t)tid * 32;
#pragma unroll
    for (int d0 = 0; d0 < 32; d0 += 8) {
      v8us a = *(const v8us*)(p0 + d0);
#pragma unroll
      for (int j = 0; j < 8; ++j)
        Vt[(d0 + j) * VTS + tid] = a[j];
    }
  }
  __syncthreads();

  // ---- Q fragments (B operand), held all chunks ----
  const u16* qrow = Qh + (size_t)(qb + l31) * 32;
  const v8bf qf0 = *(const v8bf*)(qrow + hi * 8);
  const v8bf qf1 = *(const v8bf*)(qrow + 16 + hi * 8);
  const f16* bpl = biasH + ((size_t)(hi * 512 + qb + l31)) * 4;

  const float SC2 = 0.17677669529663688f * 1.4426950408889634f;
  float lsum = 0.f;
  v16f accO = {0.f,0.f,0.f,0.f,0.f,0.f,0.f,0.f,0.f,0.f,0.f,0.f,0.f,0.f,0.f,0.f};

  v8bf ka0 = *(const v8bf*)(Kh + (size_t)l31 * 32 + hi * 8);
  v8bf ka1 = *(const v8bf*)(Kh + (size_t)l31 * 32 + 16 + hi * 8);
  v4h bb[4];
#pragma unroll
  for (int g = 0; g < 4; ++g) bb[g] = *(const v4h*)(bpl + (size_t)(g * 2) * 2048);

  v16f stC = {0.f,0.f,0.f,0.f,0.f,0.f,0.f,0.f,0.f,0.f,0.f,0.f,0.f,0.f,0.f,0.f};
  stC = __builtin_amdgcn_mfma_f32_32x32x16_bf16(ka0, qf0, stC, 0, 0, 0);
  stC = __builtin_amdgcn_mfma_f32_32x32x16_bf16(ka1, qf1, stC, 0, 0, 0);
  {
    const u16* kn = Kh + (size_t)(32 + l31) * 32;
    ka0 = *(const v8bf*)(kn + hi * 8);
    ka1 = *(const v8bf*)(kn + 16 + hi * 8);
  }

  for (int kb = 0; kb < 16; ++kb) {
    const int kbase = kb * 32;
    // QK^T(kb+1) early: matrix pipe runs under softmax VALU of chunk kb
    v16f stN = {0.f,0.f,0.f,0.f,0.f,0.f,0.f,0.f,0.f,0.f,0.f,0.f,0.f,0.f,0.f,0.f};
    __builtin_amdgcn_s_setprio(1);
    stN = __builtin_amdgcn_mfma_f32_32x32x16_bf16(ka0, qf0, stN, 0, 0, 0);
    stN = __builtin_amdgcn_mfma_f32_32x32x16_bf16(ka1, qf1, stN, 0, 0, 0);
    __builtin_amdgcn_s_setprio(0);

    // prefetch K(kb+2) and bias(kb+1)  (unconditional; reads spill into padded region = valid)
    const u16* kn = Kh + (size_t)(kbase + 64 + l31) * 32;
    const v8bf kn0 = *(const v8bf*)(kn + hi * 8);
    const v8bf kn1 = *(const v8bf*)(kn + 16 + hi * 8);
    v4h bn[4];
#pragma unroll
    for (int g = 0; g < 4; ++g)
      bn[g] = *(const v4h*)(bpl + (size_t)((kb + 1) * 8 + g * 2) * 2048);

    float p[16];
#pragma unroll
    for (int r = 0; r < 16; ++r)
      p[r] = EXP2(fmaf(stC[r], SC2, (float)bb[r >> 2][r & 3]));

    float s8[8], s4[4];
#pragma unroll
    for (int r = 0; r < 8; ++r) s8[r] = p[r] + p[r + 8];
#pragma unroll
    for (int r = 0; r < 4; ++r) s4[r] = s8[r] + s8[r + 4];
    lsum += (s4[0] + s4[2]) + (s4[1] + s4[3]);

    unsigned u[8];
#pragma unroll
    for (int t = 0; t < 8; ++t) u[t] = pk_bf16(p[2 * t], p[2 * t + 1]);
    PLSWAP(u[0], u[2]);
    PLSWAP(u[1], u[3]);
    PLSWAP(u[4], u[6]);
    PLSWAP(u[5], u[7]);
    union { v4u u; v8bf h; } cv0, cv1;
    cv0.u = (v4u){u[0], u[1], u[2], u[3]};
    cv1.u = (v4u){u[4], u[5], u[6], u[7]};

    const v8bf va0 = *(const v8bf*)&Vt[l31 * VTS + kbase + hi * 8];
    const v8bf va1 = *(const v8bf*)&Vt[l31 * VTS + kbase + 16 + hi * 8];
    __builtin_amdgcn_s_setprio(1);
    accO = __builtin_amdgcn_mfma_f32_32x32x16_bf16(va0, cv0.h, accO, 0, 0, 0);
    accO = __builtin_amdgcn_mfma_f32_32x32x16_bf16(va1, cv1.h, accO, 0, 0, 0);
    __builtin_amdgcn_s_setprio(0);

    stC = stN;
    ka0 = kn0; ka1 = kn1;
#pragma unroll
    for (int g = 0; g < 4; ++g) bb[g] = bn[g];
  }

  lsum += __shfl_xor(lsum, 32);

  const float inv = 1.0f / lsum;
  u16* orow = (u16*)outp + (size_t)(b * N_ + qb + l31) * D_ + h * 32 + 4 * hi;
#pragma unroll
  for (int g = 0; g < 4; ++g) {
    uint2 w;
    w.x = pk_bf16(accO[4 * g] * inv, accO[4 * g + 1] * inv);
    w.y = pk_bf16(accO[4 * g + 2] * inv, accO[4 * g + 3] * inv);
    *(uint2*)(orow + 8 * g) = w;
  }
}

// ---------------- LayerNorm: fp32 in; 8 rows/block, XCD-partition-aligned swizzle ----------------
// block bid -> rows (bid&7)*2048 + (bid>>3)*8 .. +8 : partition x handled by XCD x,
// matching the GEMM/attn writers so tmpf/xb stay in the local per-XCD L2.
// MODE 0 -> xb bf16 out, MODE 1 -> fp32 out
template <int MODE>
__global__ __launch_bounds__(256) void ln_kernel(
    const float* __restrict__ xin,
    const float* __restrict__ g, const float* __restrict__ b,
    float* __restrict__ xout_f32, bf16* __restrict__ xbout) {
  const int wv = threadIdx.x >> 6, ln = threadIdx.x & 63;
  const size_t row0 = ((size_t)(blockIdx.x & 7) << 11) + (size_t)(blockIdx.x >> 3) * 8 + wv * 2;
  const size_t oA = row0 * D_ + ln * 4;
  const size_t oB = oA + D_;
  const float4 vA = *(const float4*)&xin[oA];
  const float4 vB = *(const float4*)&xin[oB];
  float sA  = (vA.x + vA.y) + (vA.z + vA.w);
  float ssA = (vA.x * vA.x + vA.y * vA.y) + (vA.z * vA.z + vA.w * vA.w);
  float sB  = (vB.x + vB.y) + (vB.z + vB.w);
  float ssB = (vB.x * vB.x + vB.y * vB.y) + (vB.z * vB.z + vB.w * vB.w);
#pragma unroll
  for (int off = 1; off < 64; off <<= 1) {
    sA  += __shfl_xor(sA, off);
    ssA += __shfl_xor(ssA, off);
    sB  += __shfl_xor(sB, off);
    ssB += __shfl_xor(ssB, off);
  }
  const float muA = sA * (1.f / D_);
  const float muB = sB * (1.f / D_);
  const float rsA = rsqrtf(ssA * (1.f / D_) - muA * muA + 1e-5f);
  const float rsB = rsqrtf(ssB * (1.f / D_) - muB * muB + 1e-5f);
  const float4 gg = *(const float4*)&g[ln * 4];
  const float4 bb = *(const float4*)&b[ln * 4];
  float4 oAv, oBv;
  oAv.x = (vA.x - muA) * rsA * gg.x + bb.x;
  oAv.y = (vA.y - muA) * rsA * gg.y + bb.y;
  oAv.z = (vA.z - muA) * rsA * gg.z + bb.z;
  oAv.w = (vA.w - muA) * rsA * gg.w + bb.w;
  oBv.x = (vB.x - muB) * rsB * gg.x + bb.x;
  oBv.y = (vB.y - muB) * rsB * gg.y + bb.y;
  oBv.z = (vB.z - muB) * rsB * gg.z + bb.z;
  oBv.w = (vB.w - muB) * rsB * gg.w + bb.w;
  if constexpr (MODE == 1) {
    *(float4*)&xout_f32[oA] = oAv;
    *(float4*)&xout_f32[oB] = oBv;
  } else {
    uint2 wA, wB;
    wA.x = pk_bf16(oAv.x, oAv.y);
    wA.y = pk_bf16(oAv.z, oAv.w);
    wB.x = pk_bf16(oBv.x, oBv.y);
    wB.y = pk_bf16(oBv.z, oBv.w);
    *(uint2*)&xbout[oA] = wA;
    *(uint2*)&xbout[oB] = wB;
  }
}

extern "C" void kernel_launch(void* const* d_in, const int* in_sizes, int n_in,
                              void* d_out, int out_size, void* d_ws, size_t ws_size,
                              hipStream_t stream) {
  const float* src = (const float*)d_in[0];
  const float* e1  = (const float*)d_in[1];
  const float* e2  = (const float*)d_in[2];
  const float* Wq  = (const float*)d_in[3];
  const float* bq  = (const float*)d_in[4];
  const float* Wk  = (const float*)d_in[5];
  const float* bk  = (const float*)d_in[6];
  const float* Wv  = (const float*)d_in[7];
  const float* bv  = (const float*)d_in[8];
  const float* Wo  = (const float*)d_in[9];
  const float* bo  = (const float*)d_in[10];
  const float* W1  = (const float*)d_in[11];
  const float* b1  = (const float*)d_in[12];
  const float* W2  = (const float*)d_in[13];
  const float* b2  = (const float*)d_in[14];
  const float* g1  = (const float*)d_in[15];
  const float* be1 = (const float*)d_in[16];
  const float* g2  = (const float*)d_in[17];
  const float* be2 = (const float*)d_in[18];

  char* ws = (char*)d_ws;
  size_t off = 0;
  auto alloc = [&](size_t bytes) {
    void* p = ws + off;
    off += (bytes + 255) & ~(size_t)255;
    return p;
  };
  float*    biasP  = (float*)alloc((size_t)1024 * 1024 + 4096);  // fp32, pre-subtraction
  f16*      biasH  = (f16*)  alloc((size_t)2 * 1024 * 1024);     // fp16, 0.52MB used + prefetch pad
  unsigned* mqe    = (unsigned*)alloc((size_t)N_ * 4);
  bf16*     xb     = (bf16*) alloc((size_t)ROWS * D_ * 2);
  bf16*     attn_o = (bf16*) alloc((size_t)ROWS * D_ * 2);
  float*    tmpf   = (float*)alloc((size_t)ROWS * D_ * 4);
  bf16*     qkvh   = (bf16*) alloc((size_t)ROWS * 1024 * 2 + 65536);  // shared: head-major qkv / ffn h1
  bf16*     h1     = qkvh;
  bf16*     Wqkvt  = (bf16*) alloc((size_t)L_ * 768 * 256 * 2);
  bf16*     Wot    = (bf16*) alloc((size_t)L_ * 256 * 256 * 2);
  bf16*     W1t    = (bf16*) alloc((size_t)L_ * 1024 * 256 * 2);
  bf16*     W2t    = (bf16*) alloc((size_t)L_ * 256 * 1024 * 2);
  float*    bqkv   = (float*)alloc((size_t)L_ * 768 * 4);

  hipMemsetAsync(mqe, 0, (size_t)N_ * 4, stream);
  // biasT[k][q] = e2[k] . e1[q]  -> eK = e2, eQ = e1
  bias_gemm<<<dim3(16, 16), dim3(16, 16), 0, stream>>>(e2, e1, biasP, mqe);
  setup_all<<<7436, 256, 0, stream>>>(
      src, xb, bq, bk, bv, bqkv,
      Wq, Wk, Wv, Wo, W1, W2, Wqkvt, Wot, W1t, W2t, biasP, biasH, mqe);

  for (int l = 0; l < L_; ++l) {
    // QKV: M=16384, N=768, K=256; 128x128, head-major output
    gemm_bf16k<128, 128, 3, 0, 2, 0><<<768, 256, 0, stream>>>(
        xb, Wqkvt + (size_t)l * 196608, bqkv + l * 768, nullptr, qkvh,
        ROWS, 768, 256, 6);
    attn_k<<<512, 512, 0, stream>>>(qkvh, biasH, attn_o);
    // Wo + residual(xb): 64x128, fp32 tmpf out
    gemm_bf16k<64, 128, 4, 0, 0, 1><<<512, 256, 0, stream>>>(
        attn_o, Wot + (size_t)l * 65536, bo + l * 256, xb, tmpf,
        ROWS, 256, 256, 2);
    ln_kernel<0><<<ROWS / 8, 256, 0, stream>>>(tmpf, g1 + l * 256, be1 + l * 256, nullptr, xb);
    // W1 + ReLU: 128x256 (2/CU, single residency round), bf16 out
    gemm_bf16k<128, 256, 2, 1, 1, 0><<<512, 256, 0, stream>>>(
        xb, W1t + (size_t)l * 262144, b1 + l * 1024, nullptr, h1,
        ROWS, 1024, 256, 4);
    // W2 + residual(xb): 64x128, fp32 tmpf out
    gemm_bf16k<64, 128, 4, 0, 0, 1><<<512, 256, 0, stream>>>(
        h1, W2t + (size_t)l * 262144, b2 + l * 256, xb, tmpf,
        ROWS, 256, 1024, 2);
    if (l == L_ - 1)
      ln_kernel<1><<<ROWS / 8, 256, 0, stream>>>(tmpf, g2 + l * 256, be2 + l * 256, (float*)d_out, nullptr);
    else
      ln_kernel<0><<<ROWS / 8, 256, 0, stream>>>(tmpf, g2 + l * 256, be2 + l * 256, nullptr, xb);
  }
}